// Round 1
// baseline (675.159 us; speedup 1.0000x reference)
//
#include <hip/hip_runtime.h>
#include <hip/hip_bf16.h>

// Problem constants (SigmaMoE): B=4, T=2048 -> NT=8192 tokens
#define NT   8192
#define DM   1024
#define NE   16
#define ES   256
#define TOPK 4
#define CAP  8192   // per-expert token capacity (worst case)

typedef __attribute__((ext_vector_type(8))) short          short8;
typedef __attribute__((ext_vector_type(8))) unsigned short ushort8;
typedef __attribute__((ext_vector_type(4))) float          f32x4;

__device__ __forceinline__ unsigned short f2bf(float f){
  union { float f; unsigned u; } v; v.f = f;
  return (unsigned short)((v.u + 0x7fffu + ((v.u >> 16) & 1u)) >> 16);  // RNE
}

// ---- hidden fp32 -> bf16, row-major [NT][DM] ----
__global__ void cvt_x_kernel(const float* __restrict__ src, unsigned short* __restrict__ dst){
  size_t i = (size_t)blockIdx.x * blockDim.x + threadIdx.x;   // one thread per 8 elems
  const float4* s = reinterpret_cast<const float4*>(src) + i*2;
  float4 a = s[0], b = s[1];
  ushort8 r;
  r[0]=f2bf(a.x); r[1]=f2bf(a.y); r[2]=f2bf(a.z); r[3]=f2bf(a.w);
  r[4]=f2bf(b.x); r[5]=f2bf(b.y); r[6]=f2bf(b.z); r[7]=f2bf(b.w);
  *reinterpret_cast<ushort8*>(dst + i*8) = r;
}

// ---- [e][R][C] fp32 -> [e][C][R] bf16 (tiled transpose) ----
template<int R, int C>
__global__ void transpose_cvt_kernel(const float* __restrict__ src, unsigned short* __restrict__ dst){
  __shared__ float tile[32][33];
  const int e  = blockIdx.z;
  const int r0 = blockIdx.y * 32, c0 = blockIdx.x * 32;
  const float* sp = src + (size_t)e * R * C;
  unsigned short* dp = dst + (size_t)e * R * C;
  #pragma unroll
  for (int i = 0; i < 4; i++)
    tile[threadIdx.y + i*8][threadIdx.x] =
        sp[(size_t)(r0 + threadIdx.y + i*8) * C + c0 + threadIdx.x];
  __syncthreads();
  #pragma unroll
  for (int i = 0; i < 4; i++)
    dp[(size_t)(c0 + threadIdx.y + i*8) * R + r0 + threadIdx.x] =
        f2bf(tile[threadIdx.x][threadIdx.y + i*8]);
}

// ---- router: one wave per token; logits -> sigmoid -> top-4 -> bucket append ----
__global__ void router_kernel(const float* __restrict__ x, const float* __restrict__ sel,
                              int* __restrict__ cnt, int* __restrict__ tok,
                              float* __restrict__ gate){
  const int lane = threadIdx.x & 63;
  const int t = blockIdx.x * 4 + (threadIdx.x >> 6);
  float acc[NE];
  #pragma unroll
  for (int e = 0; e < NE; e++) acc[e] = 0.f;
  const float* xr = x + (size_t)t * DM;
  for (int i = 0; i < DM/64; i++){
    int d = lane + i*64;
    float xv = xr[d];
    const float* sr = sel + (size_t)d * NE;
    #pragma unroll
    for (int e = 0; e < NE; e++) acc[e] += xv * sr[e];
  }
  #pragma unroll
  for (int off = 32; off > 0; off >>= 1){
    #pragma unroll
    for (int e = 0; e < NE; e++) acc[e] += __shfl_xor(acc[e], off, 64);
  }
  if (lane == 0){
    unsigned used = 0;
    for (int k = 0; k < TOPK; k++){
      int best = 0; float bv = -1e30f;
      #pragma unroll
      for (int e = 0; e < NE; e++){           // strict > keeps lowest index on tie (jax top_k)
        bool ok = !((used >> e) & 1u) && (acc[e] > bv);
        if (ok){ bv = acc[e]; best = e; }
      }
      used |= 1u << best;
      float g = 1.f / (1.f + expf(-bv));      // sigmoid of selected logit
      int pos = atomicAdd(&cnt[best], 1);
      tok[best*CAP + pos]  = t;
      gate[best*CAP + pos] = g;
    }
  }
}

// ---- grouped expert FFN: block = (expert, 64-token tile), 4 waves ----
__global__ __launch_bounds__(256)
void ffn_kernel(const unsigned short* __restrict__ xb,   // [NT][DM] bf16
                const unsigned short* __restrict__ kT,   // [e][s=256][d=1024] bf16
                const unsigned short* __restrict__ vT,   // [e][d=1024][s=256] bf16
                const int* __restrict__ cnt, const int* __restrict__ tok,
                const float* __restrict__ gate, float* __restrict__ out){
  const int e  = blockIdx.y;
  const int n  = cnt[e];
  const int t0 = blockIdx.x * 64;
  if (t0 >= n) return;
  const int rows = min(64, n - t0);

  __shared__ unsigned short xs[64][72];    // 144B row stride: 16B-aligned, 2-way bank alias (free)
  __shared__ unsigned short hs[64][264];   // 528B row stride: same property
  __shared__ int   toks[64];
  __shared__ float gts[64];

  const int tid  = threadIdx.x;
  const int lane = tid & 63;
  const int wv   = tid >> 6;

  if (tid < 64){
    int idx = t0 + tid;
    toks[tid] = tok[e*CAP + (idx < n ? idx : t0)];
    gts[tid]  = (idx < n) ? gate[e*CAP + idx] : 0.f;
  }

  const unsigned short* kTe = kT + (size_t)e * ES * DM;
  const unsigned short* vTe = vT + (size_t)e * DM * ES;

  const f32x4 fzero = {0.f, 0.f, 0.f, 0.f};
  f32x4 acc1[4][4];
  #pragma unroll
  for (int m = 0; m < 4; m++)
    #pragma unroll
    for (int nn = 0; nn < 4; nn++) acc1[m][nn] = fzero;

  const int n0 = wv * 64;           // this wave's GEMM1 column slice of S=256
  const int lr = lane & 15;
  const int lk = (lane >> 4) * 8;   // k offset within the 32-wide MFMA K

  // ---- GEMM1: H[64][256] = X_tile[64][1024] @ K_e ----
  for (int kc = 0; kc < DM; kc += 64){
    __syncthreads();
    {
      int row = tid >> 2, seg = tid & 3;    // 4 threads load one row's 64-k chunk
      const unsigned short* src = xb + (size_t)toks[row]*DM + kc + seg*16;
      *reinterpret_cast<ushort8*>(&xs[row][seg*16])     = *reinterpret_cast<const ushort8*>(src);
      *reinterpret_cast<ushort8*>(&xs[row][seg*16 + 8]) = *reinterpret_cast<const ushort8*>(src + 8);
    }
    __syncthreads();
    #pragma unroll
    for (int ks = 0; ks < 64; ks += 32){
      short8 a[4];
      #pragma unroll
      for (int m = 0; m < 4; m++)
        a[m] = *reinterpret_cast<const short8*>(&xs[m*16 + lr][ks + lk]);
      #pragma unroll
      for (int nn = 0; nn < 4; nn++){
        short8 b = *reinterpret_cast<const short8*>(
            &kTe[(size_t)(n0 + nn*16 + lr)*DM + kc + ks + lk]);
        #pragma unroll
        for (int m = 0; m < 4; m++)
          acc1[m][nn] = __builtin_amdgcn_mfma_f32_16x16x32_bf16(a[m], b, acc1[m][nn], 0, 0, 0);
      }
    }
  }

  // H = bf16(gate * relu(acc1)) -> LDS
  #pragma unroll
  for (int m = 0; m < 4; m++)
    #pragma unroll
    for (int nn = 0; nn < 4; nn++)
      #pragma unroll
      for (int j = 0; j < 4; j++){
        int row = m*16 + (lane>>4)*4 + j;   // C/D layout: col=lane&15, row=(lane>>4)*4+j
        float h = fmaxf(acc1[m][nn][j], 0.f) * gts[row];
        hs[row][n0 + nn*16 + lr] = f2bf(h);
      }
  __syncthreads();

  // ---- GEMM2: out_tile[64][1024] += H @ V_e ----
  const int nB = wv * 256;          // this wave's column slice of D=1024
  for (int nc = 0; nc < 256; nc += 64){
    f32x4 acc2[4][4];
    #pragma unroll
    for (int m = 0; m < 4; m++)
      #pragma unroll
      for (int nn = 0; nn < 4; nn++) acc2[m][nn] = fzero;
    for (int ks = 0; ks < ES; ks += 32){
      short8 a[4];
      #pragma unroll
      for (int m = 0; m < 4; m++)
        a[m] = *reinterpret_cast<const short8*>(&hs[m*16 + lr][ks + lk]);
      #pragma unroll
      for (int nn = 0; nn < 4; nn++){
        short8 b = *reinterpret_cast<const short8*>(
            &vTe[(size_t)(nB + nc + nn*16 + lr)*ES + ks + lk]);
        #pragma unroll
        for (int m = 0; m < 4; m++)
          acc2[m][nn] = __builtin_amdgcn_mfma_f32_16x16x32_bf16(a[m], b, acc2[m][nn], 0, 0, 0);
      }
    }
    #pragma unroll
    for (int m = 0; m < 4; m++)
      #pragma unroll
      for (int nn = 0; nn < 4; nn++)
        #pragma unroll
        for (int j = 0; j < 4; j++){
          int row = m*16 + (lane>>4)*4 + j;
          if (row < rows)
            atomicAdd(&out[(size_t)toks[row]*DM + nB + nc + nn*16 + lr], acc2[m][nn][j]);
        }
  }
}

extern "C" void kernel_launch(void* const* d_in, const int* in_sizes, int n_in,
                              void* d_out, int out_size, void* d_ws, size_t ws_size,
                              hipStream_t stream){
  const float* hidden = (const float*)d_in[0];   // [4,2048,1024]
  const float* sel    = (const float*)d_in[1];   // [1024,16]
  const float* keys   = (const float*)d_in[2];   // [16,1024,256]
  const float* values = (const float*)d_in[3];   // [16,256,1024]
  float* out = (float*)d_out;

  char* ws = (char*)d_ws;
  unsigned short* xb = (unsigned short*)ws;                              // 16 MB
  unsigned short* kT = (unsigned short*)(ws + (size_t)16*1024*1024);     //  8 MB
  unsigned short* vT = (unsigned short*)(ws + (size_t)24*1024*1024);     //  8 MB
  int*   cnt  = (int*)  (ws + (size_t)32*1024*1024);                     // 64 B
  int*   tok  = (int*)  (ws + (size_t)32*1024*1024 + 1024);              // 512 KB
  float* gate = (float*)(ws + (size_t)32*1024*1024 + 1024
                            + (size_t)NE*CAP*sizeof(int));               // 512 KB

  hipMemsetAsync(d_out, 0, (size_t)out_size * sizeof(float), stream);    // also zeroes reg_loss
  hipMemsetAsync(cnt, 0, NE * sizeof(int), stream);

  cvt_x_kernel<<<(NT*DM/8)/256, 256, 0, stream>>>(hidden, xb);
  transpose_cvt_kernel<DM, ES><<<dim3(ES/32, DM/32, NE), dim3(32,8), 0, stream>>>(keys, kT);
  transpose_cvt_kernel<ES, DM><<<dim3(DM/32, ES/32, NE), dim3(32,8), 0, stream>>>(values, vT);
  router_kernel<<<NT/4, 256, 0, stream>>>(hidden, sel, cnt, tok, gate);
  ffn_kernel<<<dim3(CAP/64, NE), 256, 0, stream>>>(xb, kT, vT, cnt, tok, gate, out);
}

// Round 2
// 306.840 us; speedup vs baseline: 2.2004x; 2.2004x over previous
//
#include <hip/hip_runtime.h>
#include <hip/hip_bf16.h>

// Problem constants (SigmaMoE): B=4, T=2048 -> NT=8192 tokens
#define NT   8192
#define DM   1024
#define NE   16
#define ES   256
#define TOPK 4
#define CAP  8192   // per-expert token capacity (worst case)

typedef __attribute__((ext_vector_type(8))) short          short8;
typedef __attribute__((ext_vector_type(8))) unsigned short ushort8;
typedef __attribute__((ext_vector_type(4))) float          f32x4;

__device__ __forceinline__ unsigned short f2bf(float f){
  union { float f; unsigned u; } v; v.f = f;
  return (unsigned short)((v.u + 0x7fffu + ((v.u >> 16) & 1u)) >> 16);  // RNE
}

// ---- [e][R][C] fp32 -> [e][C][R] bf16 (tiled transpose) ----
template<int R, int C>
__global__ void transpose_cvt_kernel(const float* __restrict__ src, unsigned short* __restrict__ dst){
  __shared__ float tile[32][33];
  const int e  = blockIdx.z;
  const int r0 = blockIdx.y * 32, c0 = blockIdx.x * 32;
  const float* sp = src + (size_t)e * R * C;
  unsigned short* dp = dst + (size_t)e * R * C;
  #pragma unroll
  for (int i = 0; i < 4; i++)
    tile[threadIdx.y + i*8][threadIdx.x] =
        sp[(size_t)(r0 + threadIdx.y + i*8) * C + c0 + threadIdx.x];
  __syncthreads();
  #pragma unroll
  for (int i = 0; i < 4; i++)
    dp[(size_t)(c0 + threadIdx.y + i*8) * R + r0 + threadIdx.x] =
        f2bf(tile[threadIdx.x][threadIdx.y + i*8]);
}

// ---- router: block = 32 tokens, 256 threads. LDS-staged logits GEMM +
//      fused fp32->bf16 emission of hidden + block-aggregated bucketing ----
__global__ __launch_bounds__(256)
void router_kernel(const float* __restrict__ x, const float* __restrict__ sel,
                   unsigned short* __restrict__ xb,
                   int* __restrict__ cnt, int* __restrict__ tok,
                   float* __restrict__ gate){
  __shared__ float xs[32][65];        // pad 65: stride mod 32 == 1 -> conflict-free
  __shared__ float sel_lds[64][16];
  __shared__ float scr[32][17];
  __shared__ int   lcnt[NE];
  __shared__ int   gb[NE];

  const int tid = threadIdx.x;
  const int t0  = blockIdx.x * 32;
  if (tid < NE) lcnt[tid] = 0;

  const int stok = tid >> 3, dseg = tid & 7;   // staging map: 8 thr/token-row
  const int tokc = tid & 31, eg  = tid >> 5;   // compute map: 8 thr/token, 2 experts each
  float acc0 = 0.f, acc1 = 0.f;

  for (int kc = 0; kc < DM; kc += 64){
    __syncthreads();
    {   // stage sel chunk [64][16]
      int sdd = tid >> 2, se4 = (tid & 3) * 4;
      *reinterpret_cast<float4*>(&sel_lds[sdd][se4]) =
          *reinterpret_cast<const float4*>(sel + (size_t)(kc + sdd)*NE + se4);
    }
    {   // stage x chunk [32][64] + emit bf16 copy
      const float* g = x + (size_t)(t0 + stok)*DM + kc + dseg*8;
      float4 a = reinterpret_cast<const float4*>(g)[0];
      float4 b = reinterpret_cast<const float4*>(g)[1];
      ushort8 r;
      r[0]=f2bf(a.x); r[1]=f2bf(a.y); r[2]=f2bf(a.z); r[3]=f2bf(a.w);
      r[4]=f2bf(b.x); r[5]=f2bf(b.y); r[6]=f2bf(b.z); r[7]=f2bf(b.w);
      *reinterpret_cast<ushort8*>(xb + (size_t)(t0 + stok)*DM + kc + dseg*8) = r;
      float* xr = &xs[stok][dseg*8];
      xr[0]=a.x; xr[1]=a.y; xr[2]=a.z; xr[3]=a.w;
      xr[4]=b.x; xr[5]=b.y; xr[6]=b.z; xr[7]=b.w;
    }
    __syncthreads();
    #pragma unroll 8
    for (int dd = 0; dd < 64; dd++){
      float xv = xs[tokc][dd];
      float2 s = *reinterpret_cast<const float2*>(&sel_lds[dd][eg*2]);
      acc0 += xv * s.x;
      acc1 += xv * s.y;
    }
  }
  scr[tokc][eg*2]   = acc0;
  scr[tokc][eg*2+1] = acc1;
  __syncthreads();

  int best[TOPK]; float gv[TOPK]; int loff[TOPK];
  if (tid < 32){
    unsigned used = 0;
    for (int k = 0; k < TOPK; k++){
      int be = 0; float bv = -1e30f;
      #pragma unroll
      for (int e = 0; e < NE; e++){      // strict > keeps lowest index on tie (jax top_k)
        float v = scr[tid][e];
        bool ok = !((used >> e) & 1u) && (v > bv);
        if (ok){ bv = v; be = e; }
      }
      used |= 1u << be;
      best[k] = be;
      gv[k]   = 1.f / (1.f + expf(-bv));  // sigmoid of selected logit
      loff[k] = atomicAdd(&lcnt[be], 1);  // LDS-local offset
    }
  }
  __syncthreads();
  if (tid < NE) gb[tid] = atomicAdd(&cnt[tid], lcnt[tid]);  // 16 global atomics/block
  __syncthreads();
  if (tid < 32){
    int t = t0 + tid;
    #pragma unroll
    for (int k = 0; k < TOPK; k++){
      int pos = gb[best[k]] + loff[k];
      tok[best[k]*CAP + pos]  = t;
      gate[best[k]*CAP + pos] = gv[k];
    }
  }
}

// ---- grouped expert FFN: block = (expert, 64-token tile), 4 waves ----
__global__ __launch_bounds__(256)
void ffn_kernel(const unsigned short* __restrict__ xb,   // [NT][DM] bf16
                const unsigned short* __restrict__ kT,   // [e][s=256][d=1024] bf16
                const unsigned short* __restrict__ vT,   // [e][d=1024][s=256] bf16
                const int* __restrict__ cnt, const int* __restrict__ tok,
                const float* __restrict__ gate, float* __restrict__ out){
  const int e  = blockIdx.y;
  const int n  = cnt[e];
  const int t0 = blockIdx.x * 64;
  if (t0 >= n) return;
  const int rows = min(64, n - t0);

  __shared__ unsigned short xs[64][72];    // 144B row stride: 16B-aligned, 2-way bank alias (free)
  __shared__ unsigned short hs[64][264];   // 528B row stride: same property
  __shared__ int   toks[64];
  __shared__ float gts[64];

  const int tid  = threadIdx.x;
  const int lane = tid & 63;
  const int wv   = tid >> 6;

  if (tid < 64){
    int idx = t0 + tid;
    toks[tid] = tok[e*CAP + (idx < n ? idx : t0)];
    gts[tid]  = (idx < n) ? gate[e*CAP + idx] : 0.f;
  }

  const unsigned short* kTe = kT + (size_t)e * ES * DM;
  const unsigned short* vTe = vT + (size_t)e * DM * ES;

  const f32x4 fzero = {0.f, 0.f, 0.f, 0.f};
  f32x4 acc1[4][4];
  #pragma unroll
  for (int m = 0; m < 4; m++)
    #pragma unroll
    for (int nn = 0; nn < 4; nn++) acc1[m][nn] = fzero;

  const int n0 = wv * 64;           // this wave's GEMM1 column slice of S=256
  const int lr = lane & 15;
  const int lk = (lane >> 4) * 8;   // k offset within the 32-wide MFMA K

  // ---- GEMM1: H[64][256] = X_tile[64][1024] @ K_e ----
  for (int kc = 0; kc < DM; kc += 64){
    __syncthreads();
    {
      int row = tid >> 2, seg = tid & 3;    // 4 threads load one row's 64-k chunk
      const unsigned short* src = xb + (size_t)toks[row]*DM + kc + seg*16;
      *reinterpret_cast<ushort8*>(&xs[row][seg*16])     = *reinterpret_cast<const ushort8*>(src);
      *reinterpret_cast<ushort8*>(&xs[row][seg*16 + 8]) = *reinterpret_cast<const ushort8*>(src + 8);
    }
    __syncthreads();
    #pragma unroll
    for (int ks = 0; ks < 64; ks += 32){
      short8 a[4];
      #pragma unroll
      for (int m = 0; m < 4; m++)
        a[m] = *reinterpret_cast<const short8*>(&xs[m*16 + lr][ks + lk]);
      #pragma unroll
      for (int nn = 0; nn < 4; nn++){
        short8 b = *reinterpret_cast<const short8*>(
            &kTe[(size_t)(n0 + nn*16 + lr)*DM + kc + ks + lk]);
        #pragma unroll
        for (int m = 0; m < 4; m++)
          acc1[m][nn] = __builtin_amdgcn_mfma_f32_16x16x32_bf16(a[m], b, acc1[m][nn], 0, 0, 0);
      }
    }
  }

  // H = bf16(gate * relu(acc1)) -> LDS
  #pragma unroll
  for (int m = 0; m < 4; m++)
    #pragma unroll
    for (int nn = 0; nn < 4; nn++)
      #pragma unroll
      for (int j = 0; j < 4; j++){
        int row = m*16 + (lane>>4)*4 + j;   // C/D layout: col=lane&15, row=(lane>>4)*4+j
        float h = fmaxf(acc1[m][nn][j], 0.f) * gts[row];
        hs[row][n0 + nn*16 + lr] = f2bf(h);
      }
  __syncthreads();

  // ---- GEMM2: out_tile[64][1024] += H @ V_e ----
  const int nB = wv * 256;          // this wave's column slice of D=1024
  for (int nc = 0; nc < 256; nc += 64){
    f32x4 acc2[4][4];
    #pragma unroll
    for (int m = 0; m < 4; m++)
      #pragma unroll
      for (int nn = 0; nn < 4; nn++) acc2[m][nn] = fzero;
    for (int ks = 0; ks < ES; ks += 32){
      short8 a[4];
      #pragma unroll
      for (int m = 0; m < 4; m++)
        a[m] = *reinterpret_cast<const short8*>(&hs[m*16 + lr][ks + lk]);
      #pragma unroll
      for (int nn = 0; nn < 4; nn++){
        short8 b = *reinterpret_cast<const short8*>(
            &vTe[(size_t)(nB + nc + nn*16 + lr)*ES + ks + lk]);
        #pragma unroll
        for (int m = 0; m < 4; m++)
          acc2[m][nn] = __builtin_amdgcn_mfma_f32_16x16x32_bf16(a[m], b, acc2[m][nn], 0, 0, 0);
      }
    }
    #pragma unroll
    for (int m = 0; m < 4; m++)
      #pragma unroll
      for (int nn = 0; nn < 4; nn++)
        #pragma unroll
        for (int j = 0; j < 4; j++){
          int row = m*16 + (lane>>4)*4 + j;
          if (row < rows)
            atomicAdd(&out[(size_t)toks[row]*DM + nB + nc + nn*16 + lr], acc2[m][nn][j]);
        }
  }
}

extern "C" void kernel_launch(void* const* d_in, const int* in_sizes, int n_in,
                              void* d_out, int out_size, void* d_ws, size_t ws_size,
                              hipStream_t stream){
  const float* hidden = (const float*)d_in[0];   // [4,2048,1024]
  const float* sel    = (const float*)d_in[1];   // [1024,16]
  const float* keys   = (const float*)d_in[2];   // [16,1024,256]
  const float* values = (const float*)d_in[3];   // [16,256,1024]
  float* out = (float*)d_out;

  char* ws = (char*)d_ws;
  unsigned short* xb = (unsigned short*)ws;                              // 16 MB
  unsigned short* kT = (unsigned short*)(ws + (size_t)16*1024*1024);     //  8 MB
  unsigned short* vT = (unsigned short*)(ws + (size_t)24*1024*1024);     //  8 MB
  int*   cnt  = (int*)  (ws + (size_t)32*1024*1024);                     // 64 B
  int*   tok  = (int*)  (ws + (size_t)32*1024*1024 + 1024);              // 512 KB
  float* gate = (float*)(ws + (size_t)32*1024*1024 + 1024
                            + (size_t)NE*CAP*sizeof(int));               // 512 KB

  hipMemsetAsync(d_out, 0, (size_t)out_size * sizeof(float), stream);    // also zeroes reg_loss
  hipMemsetAsync(cnt, 0, NE * sizeof(int), stream);

  transpose_cvt_kernel<DM, ES><<<dim3(ES/32, DM/32, NE), dim3(32,8), 0, stream>>>(keys, kT);
  transpose_cvt_kernel<ES, DM><<<dim3(DM/32, ES/32, NE), dim3(32,8), 0, stream>>>(values, vT);
  router_kernel<<<NT/32, 256, 0, stream>>>(hidden, sel, xb, cnt, tok, gate);
  ffn_kernel<<<dim3(CAP/64, NE), 256, 0, stream>>>(xb, kT, vT, cnt, tok, gate, out);
}

// Round 3
// 300.883 us; speedup vs baseline: 2.2439x; 1.0198x over previous
//
#include <hip/hip_runtime.h>
#include <hip/hip_bf16.h>

// Problem constants (SigmaMoE): B=4, T=2048 -> NT=8192 tokens
#define NT   8192
#define DM   1024
#define NE   16
#define ES   256
#define TOPK 4
#define CAP  8192   // per-expert token capacity (worst case)

typedef __attribute__((ext_vector_type(8))) short          short8;
typedef __attribute__((ext_vector_type(8))) unsigned short ushort8;
typedef __attribute__((ext_vector_type(4))) float          f32x4;

__device__ __forceinline__ unsigned short f2bf(float f){
  union { float f; unsigned u; } v; v.f = f;
  return (unsigned short)((v.u + 0x7fffu + ((v.u >> 16) & 1u)) >> 16);  // RNE
}

// ---- [e][R][C] fp32 -> [e][C][R] bf16 (tiled transpose) ----
template<int R, int C>
__global__ void transpose_cvt_kernel(const float* __restrict__ src, unsigned short* __restrict__ dst){
  __shared__ float tile[32][33];
  const int e  = blockIdx.z;
  const int r0 = blockIdx.y * 32, c0 = blockIdx.x * 32;
  const float* sp = src + (size_t)e * R * C;
  unsigned short* dp = dst + (size_t)e * R * C;
  #pragma unroll
  for (int i = 0; i < 4; i++)
    tile[threadIdx.y + i*8][threadIdx.x] =
        sp[(size_t)(r0 + threadIdx.y + i*8) * C + c0 + threadIdx.x];
  __syncthreads();
  #pragma unroll
  for (int i = 0; i < 4; i++)
    dp[(size_t)(c0 + threadIdx.y + i*8) * R + r0 + threadIdx.x] =
        f2bf(tile[threadIdx.x][threadIdx.y + i*8]);
}

// ---- router: block = 32 tokens, 256 threads. LDS-staged logits GEMM +
//      fused fp32->bf16 emission of hidden + block-aggregated bucketing ----
__global__ __launch_bounds__(256)
void router_kernel(const float* __restrict__ x, const float* __restrict__ sel,
                   unsigned short* __restrict__ xb,
                   int* __restrict__ cnt, int* __restrict__ tok,
                   float* __restrict__ gate){
  __shared__ float xs[32][65];        // pad 65: stride mod 32 == 1 -> conflict-free
  __shared__ float sel_lds[64][16];
  __shared__ float scr[32][17];
  __shared__ int   lcnt[NE];
  __shared__ int   gb[NE];

  const int tid = threadIdx.x;
  const int t0  = blockIdx.x * 32;
  if (tid < NE) lcnt[tid] = 0;

  const int stok = tid >> 3, dseg = tid & 7;   // staging map: 8 thr/token-row
  const int tokc = tid & 31, eg  = tid >> 5;   // compute map: 8 thr/token, 2 experts each
  float acc0 = 0.f, acc1 = 0.f;

  for (int kc = 0; kc < DM; kc += 64){
    __syncthreads();
    {   // stage sel chunk [64][16]
      int sdd = tid >> 2, se4 = (tid & 3) * 4;
      *reinterpret_cast<float4*>(&sel_lds[sdd][se4]) =
          *reinterpret_cast<const float4*>(sel + (size_t)(kc + sdd)*NE + se4);
    }
    {   // stage x chunk [32][64] + emit bf16 copy
      const float* g = x + (size_t)(t0 + stok)*DM + kc + dseg*8;
      float4 a = reinterpret_cast<const float4*>(g)[0];
      float4 b = reinterpret_cast<const float4*>(g)[1];
      ushort8 r;
      r[0]=f2bf(a.x); r[1]=f2bf(a.y); r[2]=f2bf(a.z); r[3]=f2bf(a.w);
      r[4]=f2bf(b.x); r[5]=f2bf(b.y); r[6]=f2bf(b.z); r[7]=f2bf(b.w);
      *reinterpret_cast<ushort8*>(xb + (size_t)(t0 + stok)*DM + kc + dseg*8) = r;
      float* xr = &xs[stok][dseg*8];
      xr[0]=a.x; xr[1]=a.y; xr[2]=a.z; xr[3]=a.w;
      xr[4]=b.x; xr[5]=b.y; xr[6]=b.z; xr[7]=b.w;
    }
    __syncthreads();
    #pragma unroll 8
    for (int dd = 0; dd < 64; dd++){
      float xv = xs[tokc][dd];
      float2 s = *reinterpret_cast<const float2*>(&sel_lds[dd][eg*2]);
      acc0 += xv * s.x;
      acc1 += xv * s.y;
    }
  }
  scr[tokc][eg*2]   = acc0;
  scr[tokc][eg*2+1] = acc1;
  __syncthreads();

  int best[TOPK]; float gv[TOPK]; int loff[TOPK];
  if (tid < 32){
    unsigned used = 0;
    for (int k = 0; k < TOPK; k++){
      int be = 0; float bv = -1e30f;
      #pragma unroll
      for (int e = 0; e < NE; e++){      // strict > keeps lowest index on tie (jax top_k)
        float v = scr[tid][e];
        bool ok = !((used >> e) & 1u) && (v > bv);
        if (ok){ bv = v; be = e; }
      }
      used |= 1u << be;
      best[k] = be;
      gv[k]   = 1.f / (1.f + expf(-bv));  // sigmoid of selected logit
      loff[k] = atomicAdd(&lcnt[be], 1);  // LDS-local offset
    }
  }
  __syncthreads();
  if (tid < NE) gb[tid] = atomicAdd(&cnt[tid], lcnt[tid]);  // 16 global atomics/block
  __syncthreads();
  if (tid < 32){
    int t = t0 + tid;
    #pragma unroll
    for (int k = 0; k < TOPK; k++){
      int pos = gb[best[k]] + loff[k];
      tok[best[k]*CAP + pos]  = t;
      gate[best[k]*CAP + pos] = gv[k];
    }
  }
}

// ---- grouped expert FFN: flattened 1-D grid, id -> (expert = id&15, tile = id>>4).
//      Active ids are contiguous -> spread over all 256 CUs; expert e's blocks all
//      land on XCD e&7 (id%8), so kT/vT stay hot in that XCD's private L2. ----
__global__ __launch_bounds__(256)
void ffn_kernel(const unsigned short* __restrict__ xb,   // [NT][DM] bf16
                const unsigned short* __restrict__ kT,   // [e][s=256][d=1024] bf16
                const unsigned short* __restrict__ vT,   // [e][d=1024][s=256] bf16
                const int* __restrict__ cnt, const int* __restrict__ tok,
                const float* __restrict__ gate, float* __restrict__ out){
  const int e  = blockIdx.x & (NE-1);
  const int n  = cnt[e];
  const int t0 = (blockIdx.x >> 4) * 64;
  if (t0 >= n) return;
  const int rows = min(64, n - t0);

  __shared__ unsigned short xs[64][72];    // 144B row stride: 16B-aligned, 2-way bank alias (free)
  __shared__ unsigned short hs[64][264];   // 528B row stride: same property
  __shared__ int   toks[64];
  __shared__ float gts[64];

  const int tid  = threadIdx.x;
  const int lane = tid & 63;
  const int wv   = tid >> 6;

  if (tid < 64){
    int idx = t0 + tid;
    toks[tid] = tok[e*CAP + (idx < n ? idx : t0)];
    gts[tid]  = (idx < n) ? gate[e*CAP + idx] : 0.f;
  }

  const unsigned short* kTe = kT + (size_t)e * ES * DM;
  const unsigned short* vTe = vT + (size_t)e * DM * ES;

  const f32x4 fzero = {0.f, 0.f, 0.f, 0.f};
  f32x4 acc1[4][4];
  #pragma unroll
  for (int m = 0; m < 4; m++)
    #pragma unroll
    for (int nn = 0; nn < 4; nn++) acc1[m][nn] = fzero;

  const int n0 = wv * 64;           // this wave's GEMM1 column slice of S=256
  const int lr = lane & 15;
  const int lk = (lane >> 4) * 8;   // k offset within the 32-wide MFMA K

  // ---- GEMM1: H[64][256] = X_tile[64][1024] @ K_e ----
  for (int kc = 0; kc < DM; kc += 64){
    __syncthreads();
    {
      int row = tid >> 2, seg = tid & 3;    // 4 threads load one row's 64-k chunk
      const unsigned short* src = xb + (size_t)toks[row]*DM + kc + seg*16;
      *reinterpret_cast<ushort8*>(&xs[row][seg*16])     = *reinterpret_cast<const ushort8*>(src);
      *reinterpret_cast<ushort8*>(&xs[row][seg*16 + 8]) = *reinterpret_cast<const ushort8*>(src + 8);
    }
    __syncthreads();
    #pragma unroll
    for (int ks = 0; ks < 64; ks += 32){
      short8 a[4];
      #pragma unroll
      for (int m = 0; m < 4; m++)
        a[m] = *reinterpret_cast<const short8*>(&xs[m*16 + lr][ks + lk]);
      #pragma unroll
      for (int nn = 0; nn < 4; nn++){
        short8 b = *reinterpret_cast<const short8*>(
            &kTe[(size_t)(n0 + nn*16 + lr)*DM + kc + ks + lk]);
        #pragma unroll
        for (int m = 0; m < 4; m++)
          acc1[m][nn] = __builtin_amdgcn_mfma_f32_16x16x32_bf16(a[m], b, acc1[m][nn], 0, 0, 0);
      }
    }
  }

  // H = bf16(gate * relu(acc1)) -> LDS
  #pragma unroll
  for (int m = 0; m < 4; m++)
    #pragma unroll
    for (int nn = 0; nn < 4; nn++)
      #pragma unroll
      for (int j = 0; j < 4; j++){
        int row = m*16 + (lane>>4)*4 + j;   // C/D layout: col=lane&15, row=(lane>>4)*4+j
        float h = fmaxf(acc1[m][nn][j], 0.f) * gts[row];
        hs[row][n0 + nn*16 + lr] = f2bf(h);
      }
  __syncthreads();

  // ---- GEMM2: out_tile[64][1024] += H @ V_e ----
  const int nB = wv * 256;          // this wave's column slice of D=1024
  for (int nc = 0; nc < 256; nc += 64){
    f32x4 acc2[4][4];
    #pragma unroll
    for (int m = 0; m < 4; m++)
      #pragma unroll
      for (int nn = 0; nn < 4; nn++) acc2[m][nn] = fzero;
    for (int ks = 0; ks < ES; ks += 32){
      short8 a[4];
      #pragma unroll
      for (int m = 0; m < 4; m++)
        a[m] = *reinterpret_cast<const short8*>(&hs[m*16 + lr][ks + lk]);
      #pragma unroll
      for (int nn = 0; nn < 4; nn++){
        short8 b = *reinterpret_cast<const short8*>(
            &vTe[(size_t)(nB + nc + nn*16 + lr)*ES + ks + lk]);
        #pragma unroll
        for (int m = 0; m < 4; m++)
          acc2[m][nn] = __builtin_amdgcn_mfma_f32_16x16x32_bf16(a[m], b, acc2[m][nn], 0, 0, 0);
      }
    }
    #pragma unroll
    for (int m = 0; m < 4; m++)
      #pragma unroll
      for (int nn = 0; nn < 4; nn++)
        #pragma unroll
        for (int j = 0; j < 4; j++){
          int row = m*16 + (lane>>4)*4 + j;
          if (row < rows)
            atomicAdd(&out[(size_t)toks[row]*DM + nB + nc + nn*16 + lr], acc2[m][nn][j]);
        }
  }
}

extern "C" void kernel_launch(void* const* d_in, const int* in_sizes, int n_in,
                              void* d_out, int out_size, void* d_ws, size_t ws_size,
                              hipStream_t stream){
  const float* hidden = (const float*)d_in[0];   // [4,2048,1024]
  const float* sel    = (const float*)d_in[1];   // [1024,16]
  const float* keys   = (const float*)d_in[2];   // [16,1024,256]
  const float* values = (const float*)d_in[3];   // [16,256,1024]
  float* out = (float*)d_out;

  char* ws = (char*)d_ws;
  unsigned short* xb = (unsigned short*)ws;                              // 16 MB
  unsigned short* kT = (unsigned short*)(ws + (size_t)16*1024*1024);     //  8 MB
  unsigned short* vT = (unsigned short*)(ws + (size_t)24*1024*1024);     //  8 MB
  int*   cnt  = (int*)  (ws + (size_t)32*1024*1024);                     // 64 B
  int*   tok  = (int*)  (ws + (size_t)32*1024*1024 + 1024);              // 512 KB
  float* gate = (float*)(ws + (size_t)32*1024*1024 + 1024
                            + (size_t)NE*CAP*sizeof(int));               // 512 KB

  hipMemsetAsync(d_out, 0, (size_t)out_size * sizeof(float), stream);    // also zeroes reg_loss
  hipMemsetAsync(cnt, 0, NE * sizeof(int), stream);

  transpose_cvt_kernel<DM, ES><<<dim3(ES/32, DM/32, NE), dim3(32,8), 0, stream>>>(keys, kT);
  transpose_cvt_kernel<ES, DM><<<dim3(DM/32, ES/32, NE), dim3(32,8), 0, stream>>>(values, vT);
  router_kernel<<<NT/32, 256, 0, stream>>>(hidden, sel, xb, cnt, tok, gate);
  ffn_kernel<<<(CAP/64)*NE, 256, 0, stream>>>(xb, kT, vT, cnt, tok, gate, out);
}

// Round 4
// 274.533 us; speedup vs baseline: 2.4593x; 1.0960x over previous
//
#include <hip/hip_runtime.h>
#include <hip/hip_bf16.h>

// Problem constants (SigmaMoE): B=4, T=2048 -> NT=8192 tokens
#define NT   8192
#define DM   1024
#define NE   16
#define ES   256
#define TOPK 4
#define CAP  8192   // per-expert token capacity (worst case)

typedef __attribute__((ext_vector_type(8))) short          short8;
typedef __attribute__((ext_vector_type(8))) unsigned short ushort8;
typedef __attribute__((ext_vector_type(4))) float          f32x4;

__device__ __forceinline__ unsigned short f2bf(float f){
  union { float f; unsigned u; } v; v.f = f;
  return (unsigned short)((v.u + 0x7fffu + ((v.u >> 16) & 1u)) >> 16);  // RNE
}

// ---- [e][R][C] fp32 -> [e][C][R] bf16 (tiled transpose) ----
template<int R, int C>
__global__ void transpose_cvt_kernel(const float* __restrict__ src, unsigned short* __restrict__ dst){
  __shared__ float tile[32][33];
  const int e  = blockIdx.z;
  const int r0 = blockIdx.y * 32, c0 = blockIdx.x * 32;
  const float* sp = src + (size_t)e * R * C;
  unsigned short* dp = dst + (size_t)e * R * C;
  #pragma unroll
  for (int i = 0; i < 4; i++)
    tile[threadIdx.y + i*8][threadIdx.x] =
        sp[(size_t)(r0 + threadIdx.y + i*8) * C + c0 + threadIdx.x];
  __syncthreads();
  #pragma unroll
  for (int i = 0; i < 4; i++)
    dp[(size_t)(c0 + threadIdx.y + i*8) * R + r0 + threadIdx.x] =
        f2bf(tile[threadIdx.x][threadIdx.y + i*8]);
}

// ---- router: block = 32 tokens, 256 threads. LDS-staged logits GEMM +
//      fused fp32->bf16 emission of hidden + block-aggregated bucketing ----
__global__ __launch_bounds__(256)
void router_kernel(const float* __restrict__ x, const float* __restrict__ sel,
                   unsigned short* __restrict__ xb,
                   int* __restrict__ cnt, int* __restrict__ tok,
                   float* __restrict__ gate){
  __shared__ float xs[32][65];        // pad 65: stride mod 32 == 1 -> conflict-free
  __shared__ float sel_lds[64][16];
  __shared__ float scr[32][17];
  __shared__ int   lcnt[NE];
  __shared__ int   gb[NE];

  const int tid = threadIdx.x;
  const int t0  = blockIdx.x * 32;
  if (tid < NE) lcnt[tid] = 0;

  const int stok = tid >> 3, dseg = tid & 7;   // staging map: 8 thr/token-row
  const int tokc = tid & 31, eg  = tid >> 5;   // compute map: 8 thr/token, 2 experts each
  float acc0 = 0.f, acc1 = 0.f;

  for (int kc = 0; kc < DM; kc += 64){
    __syncthreads();
    {   // stage sel chunk [64][16]
      int sdd = tid >> 2, se4 = (tid & 3) * 4;
      *reinterpret_cast<float4*>(&sel_lds[sdd][se4]) =
          *reinterpret_cast<const float4*>(sel + (size_t)(kc + sdd)*NE + se4);
    }
    {   // stage x chunk [32][64] + emit bf16 copy
      const float* g = x + (size_t)(t0 + stok)*DM + kc + dseg*8;
      float4 a = reinterpret_cast<const float4*>(g)[0];
      float4 b = reinterpret_cast<const float4*>(g)[1];
      ushort8 r;
      r[0]=f2bf(a.x); r[1]=f2bf(a.y); r[2]=f2bf(a.z); r[3]=f2bf(a.w);
      r[4]=f2bf(b.x); r[5]=f2bf(b.y); r[6]=f2bf(b.z); r[7]=f2bf(b.w);
      *reinterpret_cast<ushort8*>(xb + (size_t)(t0 + stok)*DM + kc + dseg*8) = r;
      float* xr = &xs[stok][dseg*8];
      xr[0]=a.x; xr[1]=a.y; xr[2]=a.z; xr[3]=a.w;
      xr[4]=b.x; xr[5]=b.y; xr[6]=b.z; xr[7]=b.w;
    }
    __syncthreads();
    #pragma unroll 8
    for (int dd = 0; dd < 64; dd++){
      float xv = xs[tokc][dd];
      float2 s = *reinterpret_cast<const float2*>(&sel_lds[dd][eg*2]);
      acc0 += xv * s.x;
      acc1 += xv * s.y;
    }
  }
  scr[tokc][eg*2]   = acc0;
  scr[tokc][eg*2+1] = acc1;
  __syncthreads();

  int best[TOPK]; float gv[TOPK]; int loff[TOPK];
  if (tid < 32){
    unsigned used = 0;
    for (int k = 0; k < TOPK; k++){
      int be = 0; float bv = -1e30f;
      #pragma unroll
      for (int e = 0; e < NE; e++){      // strict > keeps lowest index on tie (jax top_k)
        float v = scr[tid][e];
        bool ok = !((used >> e) & 1u) && (v > bv);
        if (ok){ bv = v; be = e; }
      }
      used |= 1u << be;
      best[k] = be;
      gv[k]   = 1.f / (1.f + expf(-bv));  // sigmoid of selected logit
      loff[k] = atomicAdd(&lcnt[be], 1);  // LDS-local offset
    }
  }
  __syncthreads();
  if (tid < NE) gb[tid] = atomicAdd(&cnt[tid], lcnt[tid]);  // 16 global atomics/block
  __syncthreads();
  if (tid < 32){
    int t = t0 + tid;
    #pragma unroll
    for (int k = 0; k < TOPK; k++){
      int pos = gb[best[k]] + loff[k];
      tok[best[k]*CAP + pos]  = t;
      gate[best[k]*CAP + pos] = gv[k];
    }
  }
}

// ---- grouped expert FFN: barrier-free GEMMs, A and B direct from global.
//      Only one __syncthreads (hs produce -> consume). Compiler is free to
//      software-pipeline the 16B global loads across K iterations. ----
__global__ __launch_bounds__(256)
void ffn_kernel(const unsigned short* __restrict__ xb,   // [NT][DM] bf16
                const unsigned short* __restrict__ kT,   // [e][s=256][d=1024] bf16
                const unsigned short* __restrict__ vT,   // [e][d=1024][s=256] bf16
                const int* __restrict__ cnt, const int* __restrict__ tok,
                const float* __restrict__ gate, float* __restrict__ out){
  const int e  = blockIdx.x & (NE-1);
  const int n  = cnt[e];
  const int t0 = (blockIdx.x >> 4) * 64;
  if (t0 >= n) return;
  const int rows = min(64, n - t0);

  __shared__ unsigned short hs[64][264];   // 528B row stride
  __shared__ int   toks[64];
  __shared__ float gts[64];

  const int tid  = threadIdx.x;
  const int lane = tid & 63;
  const int wv   = tid >> 6;

  if (tid < 64){
    int idx = t0 + tid;
    toks[tid] = tok[e*CAP + (idx < n ? idx : t0)];
    gts[tid]  = (idx < n) ? gate[e*CAP + idx] : 0.f;
  }
  __syncthreads();

  const unsigned short* kTe = kT + (size_t)e * ES * DM;
  const unsigned short* vTe = vT + (size_t)e * DM * ES;

  const int n0 = wv * 64;           // this wave's GEMM1 column slice of S=256
  const int lr = lane & 15;
  const int lk = (lane >> 4) * 8;   // k offset within the 32-wide MFMA K

  // per-wave A base pointers: gathered token rows, hoisted out of the K loop
  const unsigned short* aP[4];
  #pragma unroll
  for (int m = 0; m < 4; m++)
    aP[m] = xb + (size_t)toks[m*16 + lr]*DM + lk;
  const unsigned short* bP[4];
  #pragma unroll
  for (int nn = 0; nn < 4; nn++)
    bP[nn] = kTe + (size_t)(n0 + nn*16 + lr)*DM + lk;

  const f32x4 fzero = {0.f, 0.f, 0.f, 0.f};
  f32x4 acc1[4][4];
  #pragma unroll
  for (int m = 0; m < 4; m++)
    #pragma unroll
    for (int nn = 0; nn < 4; nn++) acc1[m][nn] = fzero;

  // ---- GEMM1: H[64][256] = X_tile[64][1024] @ K_e  (no barriers) ----
  #pragma unroll 4
  for (int kk = 0; kk < DM; kk += 32){
    short8 a[4], b[4];
    #pragma unroll
    for (int m = 0; m < 4; m++)
      a[m] = *reinterpret_cast<const short8*>(aP[m] + kk);
    #pragma unroll
    for (int nn = 0; nn < 4; nn++)
      b[nn] = *reinterpret_cast<const short8*>(bP[nn] + kk);
    #pragma unroll
    for (int nn = 0; nn < 4; nn++)
      #pragma unroll
      for (int m = 0; m < 4; m++)
        acc1[m][nn] = __builtin_amdgcn_mfma_f32_16x16x32_bf16(a[m], b[nn], acc1[m][nn], 0, 0, 0);
  }

  // H = bf16(gate * relu(acc1)) -> LDS
  #pragma unroll
  for (int m = 0; m < 4; m++)
    #pragma unroll
    for (int nn = 0; nn < 4; nn++)
      #pragma unroll
      for (int j = 0; j < 4; j++){
        int row = m*16 + (lane>>4)*4 + j;   // C/D layout: col=lane&15, row=(lane>>4)*4+j
        float h = fmaxf(acc1[m][nn][j], 0.f) * gts[row];
        hs[row][n0 + nn*16 + lr] = f2bf(h);
      }
  __syncthreads();

  // ---- GEMM2: out_tile[64][1024] += H @ V_e  (no barriers) ----
  const int nB = wv * 256;          // this wave's column slice of D=1024
  const unsigned short* vB[4];
  #pragma unroll
  for (int nn = 0; nn < 4; nn++)
    vB[nn] = vTe + (size_t)(nB + nn*16 + lr)*ES + lk;

  for (int nc = 0; nc < 256; nc += 64){
    f32x4 acc2[4][4];
    #pragma unroll
    for (int m = 0; m < 4; m++)
      #pragma unroll
      for (int nn = 0; nn < 4; nn++) acc2[m][nn] = fzero;
    #pragma unroll 4
    for (int kk = 0; kk < ES; kk += 32){
      short8 a[4], b[4];
      #pragma unroll
      for (int m = 0; m < 4; m++)
        a[m] = *reinterpret_cast<const short8*>(&hs[m*16 + lr][kk + lk]);
      #pragma unroll
      for (int nn = 0; nn < 4; nn++)
        b[nn] = *reinterpret_cast<const short8*>(vB[nn] + (size_t)nc*ES + kk);
      #pragma unroll
      for (int nn = 0; nn < 4; nn++)
        #pragma unroll
        for (int m = 0; m < 4; m++)
          acc2[m][nn] = __builtin_amdgcn_mfma_f32_16x16x32_bf16(a[m], b[nn], acc2[m][nn], 0, 0, 0);
    }
    #pragma unroll
    for (int m = 0; m < 4; m++)
      #pragma unroll
      for (int nn = 0; nn < 4; nn++)
        #pragma unroll
        for (int j = 0; j < 4; j++){
          int row = m*16 + (lane>>4)*4 + j;
          if (row < rows)
            atomicAdd(&out[(size_t)toks[row]*DM + nB + nc + nn*16 + lr], acc2[m][nn][j]);
        }
  }
}

extern "C" void kernel_launch(void* const* d_in, const int* in_sizes, int n_in,
                              void* d_out, int out_size, void* d_ws, size_t ws_size,
                              hipStream_t stream){
  const float* hidden = (const float*)d_in[0];   // [4,2048,1024]
  const float* sel    = (const float*)d_in[1];   // [1024,16]
  const float* keys   = (const float*)d_in[2];   // [16,1024,256]
  const float* values = (const float*)d_in[3];   // [16,256,1024]
  float* out = (float*)d_out;

  char* ws = (char*)d_ws;
  unsigned short* xb = (unsigned short*)ws;                              // 16 MB
  unsigned short* kT = (unsigned short*)(ws + (size_t)16*1024*1024);     //  8 MB
  unsigned short* vT = (unsigned short*)(ws + (size_t)24*1024*1024);     //  8 MB
  int*   cnt  = (int*)  (ws + (size_t)32*1024*1024);                     // 64 B
  int*   tok  = (int*)  (ws + (size_t)32*1024*1024 + 1024);              // 512 KB
  float* gate = (float*)(ws + (size_t)32*1024*1024 + 1024
                            + (size_t)NE*CAP*sizeof(int));               // 512 KB

  hipMemsetAsync(d_out, 0, (size_t)out_size * sizeof(float), stream);    // also zeroes reg_loss
  hipMemsetAsync(cnt, 0, NE * sizeof(int), stream);

  transpose_cvt_kernel<DM, ES><<<dim3(ES/32, DM/32, NE), dim3(32,8), 0, stream>>>(keys, kT);
  transpose_cvt_kernel<ES, DM><<<dim3(DM/32, ES/32, NE), dim3(32,8), 0, stream>>>(values, vT);
  router_kernel<<<NT/32, 256, 0, stream>>>(hidden, sel, xb, cnt, tok, gate);
  ffn_kernel<<<(CAP/64)*NE, 256, 0, stream>>>(xb, kT, vT, cnt, tok, gate, out);
}

// Round 5
// 244.833 us; speedup vs baseline: 2.7576x; 1.1213x over previous
//
#include <hip/hip_runtime.h>
#include <hip/hip_bf16.h>

// Problem constants (SigmaMoE): B=4, T=2048 -> NT=8192 tokens
#define NT   8192
#define DM   1024
#define NE   16
#define ES   256
#define TOPK 4
#define CAP  8192   // per-expert token capacity (worst case)

typedef __attribute__((ext_vector_type(8))) short          short8;
typedef __attribute__((ext_vector_type(8))) unsigned short ushort8;
typedef __attribute__((ext_vector_type(4))) float          f32x4;

__device__ __forceinline__ unsigned short f2bf(float f){
  union { float f; unsigned u; } v; v.f = f;
  return (unsigned short)((v.u + 0x7fffu + ((v.u >> 16) & 1u)) >> 16);  // RNE
}
__device__ __forceinline__ unsigned short f2h(float f){
  union { _Float16 h; unsigned short u; } v; v.h = (_Float16)f; return v.u;  // v_cvt_f16_f32 RNE
}
__device__ __forceinline__ float h2f(unsigned short u){
  union { unsigned short u; _Float16 h; } v; v.u = u; return (float)v.h;
}

// ---- [e][R][C] fp32 -> [e][C][R] bf16 (tiled transpose) ----
template<int R, int C>
__global__ void transpose_cvt_kernel(const float* __restrict__ src, unsigned short* __restrict__ dst){
  __shared__ float tile[32][33];
  const int e  = blockIdx.z;
  const int r0 = blockIdx.y * 32, c0 = blockIdx.x * 32;
  const float* sp = src + (size_t)e * R * C;
  unsigned short* dp = dst + (size_t)e * R * C;
  #pragma unroll
  for (int i = 0; i < 4; i++)
    tile[threadIdx.y + i*8][threadIdx.x] =
        sp[(size_t)(r0 + threadIdx.y + i*8) * C + c0 + threadIdx.x];
  __syncthreads();
  #pragma unroll
  for (int i = 0; i < 4; i++)
    dp[(size_t)(c0 + threadIdx.y + i*8) * R + r0 + threadIdx.x] =
        f2bf(tile[threadIdx.x][threadIdx.y + i*8]);
}

// ---- router: block = 32 tokens, 256 threads. LDS-staged logits GEMM +
//      fused fp32->bf16 emission of hidden + block-aggregated bucketing.
//      Bucket entries carry the rank k in bits [16:17] (unique (t,k) -> slot). ----
__global__ __launch_bounds__(256)
void router_kernel(const float* __restrict__ x, const float* __restrict__ sel,
                   unsigned short* __restrict__ xb,
                   int* __restrict__ cnt, int* __restrict__ tok,
                   float* __restrict__ gate){
  __shared__ float xs[32][65];        // pad 65: stride mod 32 == 1 -> conflict-free
  __shared__ float sel_lds[64][16];
  __shared__ float scr[32][17];
  __shared__ int   lcnt[NE];
  __shared__ int   gb[NE];

  const int tid = threadIdx.x;
  const int t0  = blockIdx.x * 32;
  if (tid < NE) lcnt[tid] = 0;

  const int stok = tid >> 3, dseg = tid & 7;   // staging map: 8 thr/token-row
  const int tokc = tid & 31, eg  = tid >> 5;   // compute map: 8 thr/token, 2 experts each
  float acc0 = 0.f, acc1 = 0.f;

  for (int kc = 0; kc < DM; kc += 64){
    __syncthreads();
    {   // stage sel chunk [64][16]
      int sdd = tid >> 2, se4 = (tid & 3) * 4;
      *reinterpret_cast<float4*>(&sel_lds[sdd][se4]) =
          *reinterpret_cast<const float4*>(sel + (size_t)(kc + sdd)*NE + se4);
    }
    {   // stage x chunk [32][64] + emit bf16 copy
      const float* g = x + (size_t)(t0 + stok)*DM + kc + dseg*8;
      float4 a = reinterpret_cast<const float4*>(g)[0];
      float4 b = reinterpret_cast<const float4*>(g)[1];
      ushort8 r;
      r[0]=f2bf(a.x); r[1]=f2bf(a.y); r[2]=f2bf(a.z); r[3]=f2bf(a.w);
      r[4]=f2bf(b.x); r[5]=f2bf(b.y); r[6]=f2bf(b.z); r[7]=f2bf(b.w);
      *reinterpret_cast<ushort8*>(xb + (size_t)(t0 + stok)*DM + kc + dseg*8) = r;
      float* xr = &xs[stok][dseg*8];
      xr[0]=a.x; xr[1]=a.y; xr[2]=a.z; xr[3]=a.w;
      xr[4]=b.x; xr[5]=b.y; xr[6]=b.z; xr[7]=b.w;
    }
    __syncthreads();
    #pragma unroll 8
    for (int dd = 0; dd < 64; dd++){
      float xv = xs[tokc][dd];
      float2 s = *reinterpret_cast<const float2*>(&sel_lds[dd][eg*2]);
      acc0 += xv * s.x;
      acc1 += xv * s.y;
    }
  }
  scr[tokc][eg*2]   = acc0;
  scr[tokc][eg*2+1] = acc1;
  __syncthreads();

  int best[TOPK]; float gv[TOPK]; int loff[TOPK];
  if (tid < 32){
    unsigned used = 0;
    for (int k = 0; k < TOPK; k++){
      int be = 0; float bv = -1e30f;
      #pragma unroll
      for (int e = 0; e < NE; e++){      // strict > keeps lowest index on tie (jax top_k)
        float v = scr[tid][e];
        bool ok = !((used >> e) & 1u) && (v > bv);
        if (ok){ bv = v; be = e; }
      }
      used |= 1u << be;
      best[k] = be;
      gv[k]   = 1.f / (1.f + expf(-bv));  // sigmoid of selected logit
      loff[k] = atomicAdd(&lcnt[be], 1);  // LDS-local offset
    }
  }
  __syncthreads();
  if (tid < NE) gb[tid] = atomicAdd(&cnt[tid], lcnt[tid]);  // 16 global atomics/block
  __syncthreads();
  if (tid < 32){
    int t = t0 + tid;
    #pragma unroll
    for (int k = 0; k < TOPK; k++){
      int pos = gb[best[k]] + loff[k];
      tok[best[k]*CAP + pos]  = t | (k << 16);   // token + rank tag
      gate[best[k]*CAP + pos] = gv[k];
    }
  }
}

// ---- grouped expert FFN: 512 thr / 8 waves, barrier-free GEMMs, NO atomics:
//      each row plain-stores its fp16 partial into part[rank][token][d]. ----
__global__ __launch_bounds__(512, 4)
void ffn_kernel(const unsigned short* __restrict__ xb,   // [NT][DM] bf16
                const unsigned short* __restrict__ kT,   // [e][s=256][d=1024] bf16
                const unsigned short* __restrict__ vT,   // [e][d=1024][s=256] bf16
                const int* __restrict__ cnt, const int* __restrict__ tok,
                const float* __restrict__ gate,
                unsigned short* __restrict__ part){      // [4][NT][DM] fp16
  const int e  = blockIdx.x & (NE-1);
  const int n  = cnt[e];
  const int t0 = (blockIdx.x >> 4) * 64;
  if (t0 >= n) return;
  const int rows = min(64, n - t0);

  __shared__ unsigned short hs[64][264];   // 528B row stride
  __shared__ int   toks[64];
  __shared__ int   rnk[64];
  __shared__ float gts[64];

  const int tid  = threadIdx.x;
  const int lane = tid & 63;
  const int wv   = tid >> 6;               // 8 waves

  if (tid < 64){
    int idx = t0 + tid;
    int raw = tok[e*CAP + (idx < n ? idx : t0)];
    toks[tid] = raw & 0xFFFF;
    rnk[tid]  = raw >> 16;
    gts[tid]  = (idx < n) ? gate[e*CAP + idx] : 0.f;
  }
  __syncthreads();

  const unsigned short* kTe = kT + (size_t)e * ES * DM;
  const unsigned short* vTe = vT + (size_t)e * DM * ES;

  const int lr = lane & 15;
  const int lk = (lane >> 4) * 8;   // k offset within the 32-wide MFMA K

  // per-wave A base pointers: gathered token rows, hoisted out of the K loop
  const unsigned short* aP[4];
  #pragma unroll
  for (int m = 0; m < 4; m++)
    aP[m] = xb + (size_t)toks[m*16 + lr]*DM + lk;

  // ---- GEMM1: H[64][256] = X_tile @ K_e ; wave wv owns cols [wv*32, wv*32+32) ----
  const int n0 = wv * 32;
  const unsigned short* bP[2];
  #pragma unroll
  for (int nn = 0; nn < 2; nn++)
    bP[nn] = kTe + (size_t)(n0 + nn*16 + lr)*DM + lk;

  const f32x4 fzero = {0.f, 0.f, 0.f, 0.f};
  f32x4 acc1[4][2];
  #pragma unroll
  for (int m = 0; m < 4; m++)
    #pragma unroll
    for (int nn = 0; nn < 2; nn++) acc1[m][nn] = fzero;

  #pragma unroll 4
  for (int kk = 0; kk < DM; kk += 32){
    short8 a[4], b[2];
    #pragma unroll
    for (int m = 0; m < 4; m++)
      a[m] = *reinterpret_cast<const short8*>(aP[m] + kk);
    #pragma unroll
    for (int nn = 0; nn < 2; nn++)
      b[nn] = *reinterpret_cast<const short8*>(bP[nn] + kk);
    #pragma unroll
    for (int nn = 0; nn < 2; nn++)
      #pragma unroll
      for (int m = 0; m < 4; m++)
        acc1[m][nn] = __builtin_amdgcn_mfma_f32_16x16x32_bf16(a[m], b[nn], acc1[m][nn], 0, 0, 0);
  }

  // H = bf16(gate * relu(acc1)) -> LDS
  #pragma unroll
  for (int m = 0; m < 4; m++)
    #pragma unroll
    for (int nn = 0; nn < 2; nn++)
      #pragma unroll
      for (int j = 0; j < 4; j++){
        int row = m*16 + (lane>>4)*4 + j;   // C/D layout: col=lane&15, row=(lane>>4)*4+j
        float h = fmaxf(acc1[m][nn][j], 0.f) * gts[row];
        hs[row][n0 + nn*16 + lr] = f2bf(h);
      }
  __syncthreads();

  // ---- GEMM2: part rows = H @ V_e ; wave wv owns cols [wv*128, wv*128+128) ----
  const int nB = wv * 128;
  for (int nc = 0; nc < 128; nc += 64){
    const unsigned short* vB[4];
    #pragma unroll
    for (int nn = 0; nn < 4; nn++)
      vB[nn] = vTe + (size_t)(nB + nc + nn*16 + lr)*ES + lk;

    f32x4 acc2[4][4];
    #pragma unroll
    for (int m = 0; m < 4; m++)
      #pragma unroll
      for (int nn = 0; nn < 4; nn++) acc2[m][nn] = fzero;

    #pragma unroll 4
    for (int kk = 0; kk < ES; kk += 32){
      short8 a[4], b[4];
      #pragma unroll
      for (int m = 0; m < 4; m++)
        a[m] = *reinterpret_cast<const short8*>(&hs[m*16 + lr][kk + lk]);
      #pragma unroll
      for (int nn = 0; nn < 4; nn++)
        b[nn] = *reinterpret_cast<const short8*>(vB[nn] + kk);
      #pragma unroll
      for (int nn = 0; nn < 4; nn++)
        #pragma unroll
        for (int m = 0; m < 4; m++)
          acc2[m][nn] = __builtin_amdgcn_mfma_f32_16x16x32_bf16(a[m], b[nn], acc2[m][nn], 0, 0, 0);
    }
    #pragma unroll
    for (int m = 0; m < 4; m++)
      #pragma unroll
      for (int j = 0; j < 4; j++){
        int row = m*16 + (lane>>4)*4 + j;
        if (row < rows){
          unsigned short* pb = part + ((size_t)rnk[row]*NT + toks[row])*DM + nB + nc + lr;
          #pragma unroll
          for (int nn = 0; nn < 4; nn++)
            pb[nn*16] = f2h(acc2[m][nn][j]);
        }
      }
  }
}

// ---- gather: out[t][d] = sum_k part[k][t][d]; also writes reg_loss = 0 ----
__global__ __launch_bounds__(256)
void gather_kernel(const unsigned short* __restrict__ part, float* __restrict__ out){
  const size_t i   = (size_t)blockIdx.x * blockDim.x + threadIdx.x;  // per 8 elems
  const size_t off = i * 8;
  float s[8];
  #pragma unroll
  for (int j = 0; j < 8; j++) s[j] = 0.f;
  #pragma unroll
  for (int k = 0; k < TOPK; k++){
    ushort8 v = *reinterpret_cast<const ushort8*>(part + (size_t)k*NT*DM + off);
    #pragma unroll
    for (int j = 0; j < 8; j++) s[j] += h2f(v[j]);
  }
  float4 lo = {s[0], s[1], s[2], s[3]};
  float4 hi = {s[4], s[5], s[6], s[7]};
  reinterpret_cast<float4*>(out + off)[0] = lo;
  reinterpret_cast<float4*>(out + off)[1] = hi;
  if (i == 0) out[(size_t)NT*DM] = 0.f;   // reg_loss
}

extern "C" void kernel_launch(void* const* d_in, const int* in_sizes, int n_in,
                              void* d_out, int out_size, void* d_ws, size_t ws_size,
                              hipStream_t stream){
  const float* hidden = (const float*)d_in[0];   // [4,2048,1024]
  const float* sel    = (const float*)d_in[1];   // [1024,16]
  const float* keys   = (const float*)d_in[2];   // [16,1024,256]
  const float* values = (const float*)d_in[3];   // [16,256,1024]
  float* out = (float*)d_out;

  char* ws = (char*)d_ws;
  unsigned short* xb = (unsigned short*)ws;                              // 16 MB
  unsigned short* kT = (unsigned short*)(ws + (size_t)16*1024*1024);     //  8 MB
  unsigned short* vT = (unsigned short*)(ws + (size_t)24*1024*1024);     //  8 MB
  int*   cnt  = (int*)  (ws + (size_t)32*1024*1024);                     // 64 B
  int*   tok  = (int*)  (ws + (size_t)32*1024*1024 + 1024);              // 512 KB
  float* gate = (float*)(ws + (size_t)32*1024*1024 + 1024
                            + (size_t)NE*CAP*sizeof(int));               // 512 KB
  unsigned short* part = (unsigned short*)(ws + (size_t)34*1024*1024);   // 64 MB fp16 [4][NT][DM]

  hipMemsetAsync(cnt, 0, NE * sizeof(int), stream);

  transpose_cvt_kernel<DM, ES><<<dim3(ES/32, DM/32, NE), dim3(32,8), 0, stream>>>(keys, kT);
  transpose_cvt_kernel<ES, DM><<<dim3(DM/32, ES/32, NE), dim3(32,8), 0, stream>>>(values, vT);
  router_kernel<<<NT/32, 256, 0, stream>>>(hidden, sel, xb, cnt, tok, gate);
  ffn_kernel<<<(CAP/64)*NE, 512, 0, stream>>>(xb, kT, vT, cnt, tok, gate, part);
  gather_kernel<<<(NT*DM/8)/256, 256, 0, stream>>>(part, out);
}

// Round 6
// 189.607 us; speedup vs baseline: 3.5608x; 1.2913x over previous
//
#include <hip/hip_runtime.h>
#include <hip/hip_bf16.h>

// Problem constants (SigmaMoE): B=4, T=2048 -> NT=8192 tokens
#define NT   8192
#define DM   1024
#define NE   16
#define ES   256
#define TOPK 4
#define CAP  8192   // per-expert token capacity (worst case)

typedef __attribute__((ext_vector_type(8))) short          short8;
typedef __attribute__((ext_vector_type(8))) unsigned short ushort8;
typedef __attribute__((ext_vector_type(4))) float          f32x4;

__device__ __forceinline__ unsigned short f2bf(float f){
  union { float f; unsigned u; } v; v.f = f;
  return (unsigned short)((v.u + 0x7fffu + ((v.u >> 16) & 1u)) >> 16);  // RNE
}
__device__ __forceinline__ unsigned short f2h(float f){
  union { _Float16 h; unsigned short u; } v; v.h = (_Float16)f; return v.u;
}
__device__ __forceinline__ float h2f(unsigned short u){
  union { unsigned short u; _Float16 h; } v; v.u = u; return (float)v.h;
}

// async global->LDS, 16B/lane. LDS dest must be wave-uniform base (+lane*16 in HW).
__device__ __forceinline__ void gload16(const unsigned short* g, unsigned char* l){
  __builtin_amdgcn_global_load_lds(
      (const __attribute__((address_space(1))) unsigned int*)g,
      (__attribute__((address_space(3))) unsigned int*)l, 16, 0, 0);
}

// ---- [e][R][C] fp32 -> [e][C][R] bf16 (tiled transpose) ----
template<int R, int C>
__global__ void transpose_cvt_kernel(const float* __restrict__ src, unsigned short* __restrict__ dst){
  __shared__ float tile[32][33];
  const int e  = blockIdx.z;
  const int r0 = blockIdx.y * 32, c0 = blockIdx.x * 32;
  const float* sp = src + (size_t)e * R * C;
  unsigned short* dp = dst + (size_t)e * R * C;
  #pragma unroll
  for (int i = 0; i < 4; i++)
    tile[threadIdx.y + i*8][threadIdx.x] =
        sp[(size_t)(r0 + threadIdx.y + i*8) * C + c0 + threadIdx.x];
  __syncthreads();
  #pragma unroll
  for (int i = 0; i < 4; i++)
    dp[(size_t)(c0 + threadIdx.y + i*8) * R + r0 + threadIdx.x] =
        f2bf(tile[threadIdx.x][threadIdx.y + i*8]);
}

// ---- router: block = 32 tokens, 256 threads (unchanged from R5) ----
__global__ __launch_bounds__(256)
void router_kernel(const float* __restrict__ x, const float* __restrict__ sel,
                   unsigned short* __restrict__ xb,
                   int* __restrict__ cnt, int* __restrict__ tok,
                   float* __restrict__ gate){
  __shared__ float xs[32][65];
  __shared__ float sel_lds[64][16];
  __shared__ float scr[32][17];
  __shared__ int   lcnt[NE];
  __shared__ int   gb[NE];

  const int tid = threadIdx.x;
  const int t0  = blockIdx.x * 32;
  if (tid < NE) lcnt[tid] = 0;

  const int stok = tid >> 3, dseg = tid & 7;
  const int tokc = tid & 31, eg  = tid >> 5;
  float acc0 = 0.f, acc1 = 0.f;

  for (int kc = 0; kc < DM; kc += 64){
    __syncthreads();
    {
      int sdd = tid >> 2, se4 = (tid & 3) * 4;
      *reinterpret_cast<float4*>(&sel_lds[sdd][se4]) =
          *reinterpret_cast<const float4*>(sel + (size_t)(kc + sdd)*NE + se4);
    }
    {
      const float* g = x + (size_t)(t0 + stok)*DM + kc + dseg*8;
      float4 a = reinterpret_cast<const float4*>(g)[0];
      float4 b = reinterpret_cast<const float4*>(g)[1];
      ushort8 r;
      r[0]=f2bf(a.x); r[1]=f2bf(a.y); r[2]=f2bf(a.z); r[3]=f2bf(a.w);
      r[4]=f2bf(b.x); r[5]=f2bf(b.y); r[6]=f2bf(b.z); r[7]=f2bf(b.w);
      *reinterpret_cast<ushort8*>(xb + (size_t)(t0 + stok)*DM + kc + dseg*8) = r;
      float* xr = &xs[stok][dseg*8];
      xr[0]=a.x; xr[1]=a.y; xr[2]=a.z; xr[3]=a.w;
      xr[4]=b.x; xr[5]=b.y; xr[6]=b.z; xr[7]=b.w;
    }
    __syncthreads();
    #pragma unroll 8
    for (int dd = 0; dd < 64; dd++){
      float xv = xs[tokc][dd];
      float2 s = *reinterpret_cast<const float2*>(&sel_lds[dd][eg*2]);
      acc0 += xv * s.x;
      acc1 += xv * s.y;
    }
  }
  scr[tokc][eg*2]   = acc0;
  scr[tokc][eg*2+1] = acc1;
  __syncthreads();

  int best[TOPK]; float gv[TOPK]; int loff[TOPK];
  if (tid < 32){
    unsigned used = 0;
    for (int k = 0; k < TOPK; k++){
      int be = 0; float bv = -1e30f;
      #pragma unroll
      for (int e = 0; e < NE; e++){      // strict > keeps lowest index on tie
        float v = scr[tid][e];
        bool ok = !((used >> e) & 1u) && (v > bv);
        if (ok){ bv = v; be = e; }
      }
      used |= 1u << be;
      best[k] = be;
      gv[k]   = 1.f / (1.f + expf(-bv));
      loff[k] = atomicAdd(&lcnt[be], 1);
    }
  }
  __syncthreads();
  if (tid < NE) gb[tid] = atomicAdd(&cnt[tid], lcnt[tid]);
  __syncthreads();
  if (tid < 32){
    int t = t0 + tid;
    #pragma unroll
    for (int k = 0; k < TOPK; k++){
      int pos = gb[best[k]] + loff[k];
      tok[best[k]*CAP + pos]  = t | (k << 16);   // token + rank tag
      gate[best[k]*CAP + pos] = gv[k];
    }
  }
}

// ---- grouped expert FFN: ALL fragment reads from LDS; LDS filled by coalesced
//      global_load_lds (dbuf, 1 barrier/chunk). XOR-16B-slot swizzle everywhere:
//      linear LDS dest + inverse-swizzled GLOBAL src + swizzled ds_read. ----
__global__ __launch_bounds__(512, 2)
void ffn_kernel(const unsigned short* __restrict__ xb,   // [NT][DM] bf16
                const unsigned short* __restrict__ kT,   // [e][s=256][d=1024] bf16
                const unsigned short* __restrict__ vT,   // [e][d=1024][s=256] bf16
                const int* __restrict__ cnt, const int* __restrict__ tok,
                const float* __restrict__ gate,
                unsigned short* __restrict__ part){      // [4][NT][DM] fp16
  const int e  = blockIdx.x & (NE-1);
  const int n  = cnt[e];
  const int t0 = (blockIdx.x >> 4) * 64;
  if (t0 >= n) return;                      // block-uniform: safe w.r.t. barriers
  const int rows = min(64, n - t0);

  // sh: GEMM1 dbuf {xs[64][64] 8KB + ks[256][64] 32KB} x2 = 80KB;
  //     GEMM2 aliases it as vs[64][256] 32KB x2.
  __shared__ __align__(16) unsigned char sh[81920];
  __shared__ __align__(16) unsigned char hsb[64*512];   // H [64][256] bf16, swizzled
  __shared__ int   toks[64];
  __shared__ int   rnk[64];
  __shared__ float gts[64];

  const int tid  = threadIdx.x;
  const int lane = tid & 63;
  const int wv   = tid >> 6;                // 8 waves
  const int lr   = lane & 15;
  const int hi16 = (lane >> 4) << 4;        // k-subslot byte offset (lk*2)
  const int hi4  = (lane >> 4) * 4;
  const int xo   = (lr & 7) << 4;           // XOR swizzle term for reads

  if (tid < 64){
    int idx = t0 + tid;
    int raw = tok[e*CAP + (idx < n ? idx : t0)];
    toks[tid] = raw & 0xFFFF;
    rnk[tid]  = raw >> 16;
    gts[tid]  = (idx < n) ? gate[e*CAP + idx] : 0.f;
  }
  __syncthreads();

  const unsigned short* kTe = kT + (size_t)e * ES * DM;
  const unsigned short* vTe = vT + (size_t)e * DM * ES;

  // staging sources (cols pre-swizzled so linear LDS + swizzled read is consistent)
  const int c0  = ((tid & 7) ^ ((tid >> 3) & 7)) * 8;      // 128B-row tiles (xs/ks)
  const unsigned short* xsrc = xb  + (size_t)toks[tid >> 3]*DM + c0;
  const unsigned short* ksrc = kTe + (size_t)(tid >> 3)*DM + c0;
  const int c0v = ((tid & 31) ^ ((tid >> 5) & 7)) * 8;     // 512B-row tiles (vs)
  const unsigned short* vsrc = vTe + (size_t)(tid >> 5)*ES + c0v;

  unsigned char* myx[2]; unsigned char* myk[2]; unsigned char* myv[2];
  #pragma unroll
  for (int q = 0; q < 2; q++){
    myx[q] = sh + q*40960 + wv*1024;
    myk[q] = sh + q*40960 + 8192 + wv*1024;
    myv[q] = sh + q*32768 + wv*1024;
  }

  const int mh = wv >> 2, nq = wv & 3;      // wave tile: 32 rows x 64 S-cols

  // prologue: stage chunk 0 (X 8KB: 1 instr/wave; kT 32KB: 4 instr/wave)
  gload16(xsrc, myx[0]);
  #pragma unroll
  for (int i = 0; i < 4; i++)
    gload16(ksrc + (size_t)i*64*DM, myk[0] + i*8192);

  const f32x4 fz = {0.f,0.f,0.f,0.f};
  f32x4 acc1[2][4];
  #pragma unroll
  for (int m = 0; m < 2; m++)
    #pragma unroll
    for (int nn = 0; nn < 4; nn++) acc1[m][nn] = fz;

  __syncthreads();                          // chunk 0 staged

  // ---- GEMM1: H[64][256] = X_tile @ K_e, BK=64, 16 chunks ----
  int p = 0;
  for (int t = 0; t < 16; t++){
    if (t < 15){
      int kc = (t+1)*64;
      gload16(xsrc + kc, myx[p^1]);
      #pragma unroll
      for (int i = 0; i < 4; i++)
        gload16(ksrc + kc + (size_t)i*64*DM, myk[p^1] + i*8192);
    }
    const unsigned char* xsb = sh + p*40960;
    const unsigned char* ksb = xsb + 8192;
    #pragma unroll
    for (int kk = 0; kk < 2; kk++){
      int kb = kk*64 + hi16;
      short8 a[2], b[4];
      #pragma unroll
      for (int m = 0; m < 2; m++)
        a[m] = *reinterpret_cast<const short8*>(xsb + (mh*32 + m*16 + lr)*128 + (kb ^ xo));
      #pragma unroll
      for (int nn = 0; nn < 4; nn++)
        b[nn] = *reinterpret_cast<const short8*>(ksb + (nq*64 + nn*16 + lr)*128 + (kb ^ xo));
      #pragma unroll
      for (int nn = 0; nn < 4; nn++)
        #pragma unroll
        for (int m = 0; m < 2; m++)
          acc1[m][nn] = __builtin_amdgcn_mfma_f32_16x16x32_bf16(a[m], b[nn], acc1[m][nn], 0,0,0);
    }
    __syncthreads();                        // stage(t+1) done + buf p free
    p ^= 1;
  }
  // p == 0 here

  // stage V chunk 0 (GEMM1 bufs dead past the last barrier); overlap with hs write
  #pragma unroll
  for (int i = 0; i < 4; i++)
    gload16(vsrc + (size_t)i*16*ES, myv[0] + i*8192);

  // H = bf16(gate * relu(acc1)) -> swizzled hsb
  #pragma unroll
  for (int m = 0; m < 2; m++)
    #pragma unroll
    for (int j = 0; j < 4; j++){
      int row = mh*32 + m*16 + hi4 + j;     // C/D: col=lane&15, row=(lane>>4)*4+j
      float g = gts[row];
      unsigned char* rbase = hsb + row*512;
      int rxo = (row & 7) << 4;
      #pragma unroll
      for (int nn = 0; nn < 4; nn++){
        int colb = (nq*64 + nn*16 + lr) * 2;
        float h = fmaxf(acc1[m][nn][j], 0.f) * g;
        *reinterpret_cast<unsigned short*>(rbase + (colb ^ rxo)) = f2bf(h);
      }
    }
  __syncthreads();                          // hs visible + vs(0) staged

  // ---- GEMM2: part rows = H @ V_e, 16 d-chunks of 64; wave = 32 rows x 16 d ----
  const int dq = nq;
  p = 0;
  for (int t = 0; t < 16; t++){
    if (t < 15){
      int d0n = (t+1)*64;
      #pragma unroll
      for (int i = 0; i < 4; i++)
        gload16(vsrc + (size_t)(d0n + i*16)*ES, myv[p^1] + i*8192);
    }
    const unsigned char* vsb = sh + p*32768;
    f32x4 acc2[2] = {fz, fz};
    #pragma unroll
    for (int kk = 0; kk < 8; kk++){
      int kb = kk*64 + hi16;
      short8 a0 = *reinterpret_cast<const short8*>(hsb + (mh*32 + lr)*512      + (kb ^ xo));
      short8 a1 = *reinterpret_cast<const short8*>(hsb + (mh*32 + 16 + lr)*512 + (kb ^ xo));
      short8 b  = *reinterpret_cast<const short8*>(vsb + (dq*16 + lr)*512      + (kb ^ xo));
      acc2[0] = __builtin_amdgcn_mfma_f32_16x16x32_bf16(a0, b, acc2[0], 0,0,0);
      acc2[1] = __builtin_amdgcn_mfma_f32_16x16x32_bf16(a1, b, acc2[1], 0,0,0);
    }
    int d0 = t*64;
    #pragma unroll
    for (int m = 0; m < 2; m++)
      #pragma unroll
      for (int j = 0; j < 4; j++){
        int row = mh*32 + m*16 + hi4 + j;
        if (row < rows)
          part[((size_t)rnk[row]*NT + toks[row])*DM + d0 + dq*16 + lr] = f2h(acc2[m][j]);
      }
    __syncthreads();
    p ^= 1;
  }
}

// ---- gather: out[t][d] = sum_k part[k][t][d]; also writes reg_loss = 0 ----
__global__ __launch_bounds__(256)
void gather_kernel(const unsigned short* __restrict__ part, float* __restrict__ out){
  const size_t i   = (size_t)blockIdx.x * blockDim.x + threadIdx.x;
  const size_t off = i * 8;
  float s[8];
  #pragma unroll
  for (int j = 0; j < 8; j++) s[j] = 0.f;
  #pragma unroll
  for (int k = 0; k < TOPK; k++){
    ushort8 v = *reinterpret_cast<const ushort8*>(part + (size_t)k*NT*DM + off);
    #pragma unroll
    for (int j = 0; j < 8; j++) s[j] += h2f(v[j]);
  }
  float4 lo = {s[0], s[1], s[2], s[3]};
  float4 hi = {s[4], s[5], s[6], s[7]};
  reinterpret_cast<float4*>(out + off)[0] = lo;
  reinterpret_cast<float4*>(out + off)[1] = hi;
  if (i == 0) out[(size_t)NT*DM] = 0.f;   // reg_loss
}

extern "C" void kernel_launch(void* const* d_in, const int* in_sizes, int n_in,
                              void* d_out, int out_size, void* d_ws, size_t ws_size,
                              hipStream_t stream){
  const float* hidden = (const float*)d_in[0];   // [4,2048,1024]
  const float* sel    = (const float*)d_in[1];   // [1024,16]
  const float* keys   = (const float*)d_in[2];   // [16,1024,256]
  const float* values = (const float*)d_in[3];   // [16,256,1024]
  float* out = (float*)d_out;

  char* ws = (char*)d_ws;
  unsigned short* xb = (unsigned short*)ws;                              // 16 MB
  unsigned short* kT = (unsigned short*)(ws + (size_t)16*1024*1024);     //  8 MB
  unsigned short* vT = (unsigned short*)(ws + (size_t)24*1024*1024);     //  8 MB
  int*   cnt  = (int*)  (ws + (size_t)32*1024*1024);                     // 64 B
  int*   tok  = (int*)  (ws + (size_t)32*1024*1024 + 1024);              // 512 KB
  float* gate = (float*)(ws + (size_t)32*1024*1024 + 1024
                            + (size_t)NE*CAP*sizeof(int));               // 512 KB
  unsigned short* part = (unsigned short*)(ws + (size_t)34*1024*1024);   // 64 MB fp16 [4][NT][DM]

  hipMemsetAsync(cnt, 0, NE * sizeof(int), stream);

  transpose_cvt_kernel<DM, ES><<<dim3(ES/32, DM/32, NE), dim3(32,8), 0, stream>>>(keys, kT);
  transpose_cvt_kernel<ES, DM><<<dim3(DM/32, ES/32, NE), dim3(32,8), 0, stream>>>(values, vT);
  router_kernel<<<NT/32, 256, 0, stream>>>(hidden, sel, xb, cnt, tok, gate);
  ffn_kernel<<<(CAP/64)*NE, 512, 0, stream>>>(xb, kT, vT, cnt, tok, gate, part);
  gather_kernel<<<(NT*DM/8)/256, 256, 0, stream>>>(part, out);
}

// Round 7
// 175.161 us; speedup vs baseline: 3.8545x; 1.0825x over previous
//
#include <hip/hip_runtime.h>
#include <hip/hip_bf16.h>

// Problem constants (SigmaMoE): B=4, T=2048 -> NT=8192 tokens
#define NT   8192
#define DM   1024
#define NE   16
#define ES   256
#define TOPK 4
#define CAP  8192   // per-expert token capacity (worst case)

typedef __attribute__((ext_vector_type(8))) short          short8;
typedef __attribute__((ext_vector_type(8))) unsigned short ushort8;
typedef __attribute__((ext_vector_type(4))) float          f32x4;

__device__ __forceinline__ unsigned short f2bf(float f){
  union { float f; unsigned u; } v; v.f = f;
  return (unsigned short)((v.u + 0x7fffu + ((v.u >> 16) & 1u)) >> 16);  // RNE
}
__device__ __forceinline__ unsigned short f2h(float f){
  union { _Float16 h; unsigned short u; } v; v.h = (_Float16)f; return v.u;
}
__device__ __forceinline__ float h2f(unsigned short u){
  union { unsigned short u; _Float16 h; } v; v.u = u; return (float)v.h;
}

// async global->LDS, 16B/lane. LDS dest = wave-uniform base (+lane*16 in HW).
__device__ __forceinline__ void gload16(const unsigned short* g, unsigned char* l){
  __builtin_amdgcn_global_load_lds(
      (const __attribute__((address_space(1))) unsigned int*)g,
      (__attribute__((address_space(3))) unsigned int*)l, 16, 0, 0);
}

// ---- [e][R][C] fp32 -> [e][C][R] bf16 (tiled transpose) ----
template<int R, int C>
__global__ void transpose_cvt_kernel(const float* __restrict__ src, unsigned short* __restrict__ dst){
  __shared__ float tile[32][33];
  const int e  = blockIdx.z;
  const int r0 = blockIdx.y * 32, c0 = blockIdx.x * 32;
  const float* sp = src + (size_t)e * R * C;
  unsigned short* dp = dst + (size_t)e * R * C;
  #pragma unroll
  for (int i = 0; i < 4; i++)
    tile[threadIdx.y + i*8][threadIdx.x] =
        sp[(size_t)(r0 + threadIdx.y + i*8) * C + c0 + threadIdx.x];
  __syncthreads();
  #pragma unroll
  for (int i = 0; i < 4; i++)
    dp[(size_t)(c0 + threadIdx.y + i*8) * R + r0 + threadIdx.x] =
        f2bf(tile[threadIdx.x][threadIdx.y + i*8]);
}

// ---- router: block = 32 tokens, 256 threads (unchanged) ----
__global__ __launch_bounds__(256)
void router_kernel(const float* __restrict__ x, const float* __restrict__ sel,
                   unsigned short* __restrict__ xb,
                   int* __restrict__ cnt, int* __restrict__ tok,
                   float* __restrict__ gate){
  __shared__ float xs[32][65];
  __shared__ float sel_lds[64][16];
  __shared__ float scr[32][17];
  __shared__ int   lcnt[NE];
  __shared__ int   gb[NE];

  const int tid = threadIdx.x;
  const int t0  = blockIdx.x * 32;
  if (tid < NE) lcnt[tid] = 0;

  const int stok = tid >> 3, dseg = tid & 7;
  const int tokc = tid & 31, eg  = tid >> 5;
  float acc0 = 0.f, acc1 = 0.f;

  for (int kc = 0; kc < DM; kc += 64){
    __syncthreads();
    {
      int sdd = tid >> 2, se4 = (tid & 3) * 4;
      *reinterpret_cast<float4*>(&sel_lds[sdd][se4]) =
          *reinterpret_cast<const float4*>(sel + (size_t)(kc + sdd)*NE + se4);
    }
    {
      const float* g = x + (size_t)(t0 + stok)*DM + kc + dseg*8;
      float4 a = reinterpret_cast<const float4*>(g)[0];
      float4 b = reinterpret_cast<const float4*>(g)[1];
      ushort8 r;
      r[0]=f2bf(a.x); r[1]=f2bf(a.y); r[2]=f2bf(a.z); r[3]=f2bf(a.w);
      r[4]=f2bf(b.x); r[5]=f2bf(b.y); r[6]=f2bf(b.z); r[7]=f2bf(b.w);
      *reinterpret_cast<ushort8*>(xb + (size_t)(t0 + stok)*DM + kc + dseg*8) = r;
      float* xr = &xs[stok][dseg*8];
      xr[0]=a.x; xr[1]=a.y; xr[2]=a.z; xr[3]=a.w;
      xr[4]=b.x; xr[5]=b.y; xr[6]=b.z; xr[7]=b.w;
    }
    __syncthreads();
    #pragma unroll 8
    for (int dd = 0; dd < 64; dd++){
      float xv = xs[tokc][dd];
      float2 s = *reinterpret_cast<const float2*>(&sel_lds[dd][eg*2]);
      acc0 += xv * s.x;
      acc1 += xv * s.y;
    }
  }
  scr[tokc][eg*2]   = acc0;
  scr[tokc][eg*2+1] = acc1;
  __syncthreads();

  int best[TOPK]; float gv[TOPK]; int loff[TOPK];
  if (tid < 32){
    unsigned used = 0;
    for (int k = 0; k < TOPK; k++){
      int be = 0; float bv = -1e30f;
      #pragma unroll
      for (int e = 0; e < NE; e++){      // strict > keeps lowest index on tie
        float v = scr[tid][e];
        bool ok = !((used >> e) & 1u) && (v > bv);
        if (ok){ bv = v; be = e; }
      }
      used |= 1u << be;
      best[k] = be;
      gv[k]   = 1.f / (1.f + expf(-bv));
      loff[k] = atomicAdd(&lcnt[be], 1);
    }
  }
  __syncthreads();
  if (tid < NE) gb[tid] = atomicAdd(&cnt[tid], lcnt[tid]);
  __syncthreads();
  if (tid < 32){
    int t = t0 + tid;
    #pragma unroll
    for (int k = 0; k < TOPK; k++){
      int pos = gb[best[k]] + loff[k];
      tok[best[k]*CAP + pos]  = t | (k << 16);   // token + rank tag
      gate[best[k]*CAP + pos] = gv[k];
    }
  }
}

// ---- grouped expert FFN: 128-token block, 8 waves, wave tile 64x64 (0.5 LDS
//      reads/MFMA). GEMM1: BK=32 dbuf {X 8KB + K 16KB}. GEMM2: 4 d-passes x
//      8 s-chunks, V staged [256d][32s] dbuf; A from hsb, B from V; stores
//      stay d-coalesced into part. XOR-slot swizzle on all tiles. ----
__global__ __launch_bounds__(512, 2)
void ffn_kernel(const unsigned short* __restrict__ xb,   // [NT][DM] bf16
                const unsigned short* __restrict__ kT,   // [e][s=256][d=1024] bf16
                const unsigned short* __restrict__ vT,   // [e][d=1024][s=256] bf16
                const int* __restrict__ cnt, const int* __restrict__ tok,
                const float* __restrict__ gate,
                unsigned short* __restrict__ part){      // [4][NT][DM] fp16
  const int e  = blockIdx.x & (NE-1);
  const int n  = cnt[e];
  const int t0 = (blockIdx.x >> 4) * 128;
  if (t0 >= n) return;                      // block-uniform
  const int rows = min(128, n - t0);

  // sh: GEMM1 dbuf {X[128][32] 8KB @0 + K[256][32] 16KB @8192} x2 = 48KB;
  //     GEMM2 aliases as vs[256][32] 16KB x2 (@0, @16384).
  __shared__ __align__(16) unsigned char sh[49152];
  __shared__ __align__(16) unsigned char hsb[128*512];   // H [128][256] bf16, swizzled
  __shared__ int   toks[128];
  __shared__ int   rnk[128];
  __shared__ float gts[128];

  const int tid  = threadIdx.x;
  const int lane = tid & 63;
  const int wv   = tid >> 6;                // 8 waves
  const int lr   = lane & 15;
  const int kb16 = (lane >> 4) << 4;        // k-group byte offset
  const int hi4  = (lane >> 4) * 4;
  const int xo4  = (lr & 3) << 4;           // swizzle for 64B-row tiles
  const int xo8  = (lr & 7) << 4;           // swizzle for 512B-row hsb

  if (tid < 128){
    int idx = t0 + tid;
    int raw = tok[e*CAP + (idx < n ? idx : t0)];
    toks[tid] = raw & 0xFFFF;
    rnk[tid]  = raw >> 16;
    gts[tid]  = (idx < n) ? gate[e*CAP + idx] : 0.f;
  }
  __syncthreads();

  const unsigned short* kTe = kT + (size_t)e * ES * DM;
  const unsigned short* vTe = vT + (size_t)e * DM * ES;

  // staging maps: thread -> (row = tid>>2, slot = tid&3), source col pre-swizzled
  const int srow = tid >> 2;
  const int scol = ((tid & 3) ^ (srow & 3)) * 8;
  const unsigned short* xsrc  = xb  + (size_t)toks[srow]*DM + scol;
  const unsigned short* ksrc0 = kTe + (size_t)srow*DM        + scol;
  const unsigned short* ksrc1 = kTe + (size_t)(128 + srow)*DM + scol;
  const unsigned short* vsrc0 = vTe + (size_t)srow*ES        + scol;
  const unsigned short* vsrc1 = vTe + (size_t)(128 + srow)*ES + scol;

  const int mh = wv >> 2;                   // token half   (64 rows)
  const int nq = wv & 3;                    // S/d quarter  (64 cols)

  // prologue: stage GEMM1 chunk 0
  gload16(xsrc,  sh + wv*1024);
  gload16(ksrc0, sh + 8192  + wv*1024);
  gload16(ksrc1, sh + 16384 + wv*1024);

  const f32x4 fz = {0.f,0.f,0.f,0.f};
  f32x4 acc1[4][4];
  #pragma unroll
  for (int m = 0; m < 4; m++)
    #pragma unroll
    for (int nn = 0; nn < 4; nn++) acc1[m][nn] = fz;

  __syncthreads();                          // chunk 0 staged

  // ---- GEMM1: H[128][256] = X_tile @ K_e, BK=32, 32 chunks ----
  int q = 0;
  for (int c = 0; c < 32; c++){
    if (c < 31){
      int kc = (c+1)*32;
      unsigned char* bb = sh + (q^1)*24576;
      gload16(xsrc  + kc, bb + wv*1024);
      gload16(ksrc0 + kc, bb + 8192  + wv*1024);
      gload16(ksrc1 + kc, bb + 16384 + wv*1024);
    } else {
      // stage V chunk 0 (pass 0, s 0..31) into sh+0 (buf0 dead since c==30)
      gload16(vsrc0, sh + wv*1024);
      gload16(vsrc1, sh + 8192 + wv*1024);
    }
    const unsigned char* xl = sh + q*24576;
    const unsigned char* kl = xl + 8192;
    short8 a[4], b[4];
    #pragma unroll
    for (int m = 0; m < 4; m++)
      a[m] = *reinterpret_cast<const short8*>(xl + (mh*64 + m*16 + lr)*64 + (kb16 ^ xo4));
    #pragma unroll
    for (int nn = 0; nn < 4; nn++)
      b[nn] = *reinterpret_cast<const short8*>(kl + (nq*64 + nn*16 + lr)*64 + (kb16 ^ xo4));
    #pragma unroll
    for (int nn = 0; nn < 4; nn++)
      #pragma unroll
      for (int m = 0; m < 4; m++)
        acc1[m][nn] = __builtin_amdgcn_mfma_f32_16x16x32_bf16(a[m], b[nn], acc1[m][nn], 0,0,0);
    __syncthreads();
    q ^= 1;
  }

  // H = bf16(gate * relu(acc1)) -> swizzled hsb
  #pragma unroll
  for (int m = 0; m < 4; m++)
    #pragma unroll
    for (int j = 0; j < 4; j++){
      int row = mh*64 + m*16 + hi4 + j;     // C/D: col=lane&15, row=(lane>>4)*4+j
      float g = gts[row];
      unsigned char* rbase = hsb + row*512;
      int rxo = (row & 7) << 4;
      #pragma unroll
      for (int nn = 0; nn < 4; nn++){
        int colb = (nq*64 + nn*16 + lr) * 2;
        float h = fmaxf(acc1[m][nn][j], 0.f) * g;
        *reinterpret_cast<unsigned short*>(rbase + (colb ^ rxo)) = f2bf(h);
      }
    }
  __syncthreads();                          // hsb visible; vs chunk 0 drained earlier

  // ---- GEMM2: part = H @ V_e. 4 d-passes (256 each) x 8 s-chunks (32 each).
  //      A = hsb token-lines, B = staged V d-lines; D[tok][d]. ----
  f32x4 acc2[4][4];
  #pragma unroll
  for (int m = 0; m < 4; m++)
    #pragma unroll
    for (int nn = 0; nn < 4; nn++) acc2[m][nn] = fz;

  for (int cc = 0; cc < 32; cc++){
    if (cc < 31){
      int p4n = (cc+1) >> 3, cn = (cc+1) & 7;
      unsigned char* vb = sh + ((cc+1)&1)*16384;
      const size_t soff = (size_t)p4n*256*ES + cn*32;
      gload16(vsrc0 + soff, vb + wv*1024);
      gload16(vsrc1 + soff, vb + 8192 + wv*1024);
    }
    const unsigned char* vl = sh + (cc&1)*16384;
    const int sb = (cc & 7) * 64;
    short8 a[4], b[4];
    #pragma unroll
    for (int m = 0; m < 4; m++)
      a[m] = *reinterpret_cast<const short8*>(hsb + (mh*64 + m*16 + lr)*512 + ((sb + kb16) ^ xo8));
    #pragma unroll
    for (int nn = 0; nn < 4; nn++)
      b[nn] = *reinterpret_cast<const short8*>(vl + (nq*64 + nn*16 + lr)*64 + (kb16 ^ xo4));
    #pragma unroll
    for (int nn = 0; nn < 4; nn++)
      #pragma unroll
      for (int m = 0; m < 4; m++)
        acc2[m][nn] = __builtin_amdgcn_mfma_f32_16x16x32_bf16(a[m], b[nn], acc2[m][nn], 0,0,0);

    if ((cc & 7) == 7){                     // end of a d-pass: write + reset
      int p4 = cc >> 3;
      #pragma unroll
      for (int m = 0; m < 4; m++)
        #pragma unroll
        for (int j = 0; j < 4; j++){
          int tokl = mh*64 + m*16 + hi4 + j;
          if (tokl < rows){
            unsigned short* pb = part + ((size_t)rnk[tokl]*NT + toks[tokl])*DM
                                      + p4*256 + nq*64 + lr;
            #pragma unroll
            for (int nn = 0; nn < 4; nn++)
              pb[nn*16] = f2h(acc2[m][nn][j]);
          }
        }
      #pragma unroll
      for (int m = 0; m < 4; m++)
        #pragma unroll
        for (int nn = 0; nn < 4; nn++) acc2[m][nn] = fz;
    }
    __syncthreads();
  }
}

// ---- gather: out[t][d] = sum_k part[k][t][d]; also writes reg_loss = 0 ----
__global__ __launch_bounds__(256)
void gather_kernel(const unsigned short* __restrict__ part, float* __restrict__ out){
  const size_t i   = (size_t)blockIdx.x * blockDim.x + threadIdx.x;
  const size_t off = i * 8;
  float s[8];
  #pragma unroll
  for (int j = 0; j < 8; j++) s[j] = 0.f;
  #pragma unroll
  for (int k = 0; k < TOPK; k++){
    ushort8 v = *reinterpret_cast<const ushort8*>(part + (size_t)k*NT*DM + off);
    #pragma unroll
    for (int j = 0; j < 8; j++) s[j] += h2f(v[j]);
  }
  float4 lo = {s[0], s[1], s[2], s[3]};
  float4 hi = {s[4], s[5], s[6], s[7]};
  reinterpret_cast<float4*>(out + off)[0] = lo;
  reinterpret_cast<float4*>(out + off)[1] = hi;
  if (i == 0) out[(size_t)NT*DM] = 0.f;   // reg_loss
}

extern "C" void kernel_launch(void* const* d_in, const int* in_sizes, int n_in,
                              void* d_out, int out_size, void* d_ws, size_t ws_size,
                              hipStream_t stream){
  const float* hidden = (const float*)d_in[0];   // [4,2048,1024]
  const float* sel    = (const float*)d_in[1];   // [1024,16]
  const float* keys   = (const float*)d_in[2];   // [16,1024,256]
  const float* values = (const float*)d_in[3];   // [16,256,1024]
  float* out = (float*)d_out;

  char* ws = (char*)d_ws;
  unsigned short* xb = (unsigned short*)ws;                              // 16 MB
  unsigned short* kT = (unsigned short*)(ws + (size_t)16*1024*1024);     //  8 MB
  unsigned short* vT = (unsigned short*)(ws + (size_t)24*1024*1024);     //  8 MB
  int*   cnt  = (int*)  (ws + (size_t)32*1024*1024);                     // 64 B
  int*   tok  = (int*)  (ws + (size_t)32*1024*1024 + 1024);              // 512 KB
  float* gate = (float*)(ws + (size_t)32*1024*1024 + 1024
                            + (size_t)NE*CAP*sizeof(int));               // 512 KB
  unsigned short* part = (unsigned short*)(ws + (size_t)34*1024*1024);   // 64 MB fp16 [4][NT][DM]

  hipMemsetAsync(cnt, 0, NE * sizeof(int), stream);

  transpose_cvt_kernel<DM, ES><<<dim3(ES/32, DM/32, NE), dim3(32,8), 0, stream>>>(keys, kT);
  transpose_cvt_kernel<ES, DM><<<dim3(DM/32, ES/32, NE), dim3(32,8), 0, stream>>>(values, vT);
  router_kernel<<<NT/32, 256, 0, stream>>>(hidden, sel, xb, cnt, tok, gate);
  ffn_kernel<<<(CAP/128)*NE, 512, 0, stream>>>(xb, kT, vT, cnt, tok, gate, part);
  gather_kernel<<<(NT*DM/8)/256, 256, 0, stream>>>(part, out);
}

// Round 8
// 144.003 us; speedup vs baseline: 4.6885x; 1.2164x over previous
//
#include <hip/hip_runtime.h>
#include <hip/hip_bf16.h>

// Problem constants (SigmaMoE): B=4, T=2048 -> NT=8192 tokens
#define NT   8192
#define DM   1024
#define NE   16
#define ES   256
#define TOPK 4
#define CAP  8192   // per-expert token capacity (worst case)

typedef __attribute__((ext_vector_type(8))) short          short8;
typedef __attribute__((ext_vector_type(8))) unsigned short ushort8;
typedef __attribute__((ext_vector_type(4))) float          f32x4;

__device__ __forceinline__ unsigned short f2bf(float f){
  union { float f; unsigned u; } v; v.f = f;
  return (unsigned short)((v.u + 0x7fffu + ((v.u >> 16) & 1u)) >> 16);  // RNE
}
__device__ __forceinline__ unsigned short f2h(float f){
  union { _Float16 h; unsigned short u; } v; v.h = (_Float16)f; return v.u;
}
__device__ __forceinline__ float h2f(unsigned short u){
  union { unsigned short u; _Float16 h; } v; v.u = u; return (float)v.h;
}

// async global->LDS, 16B/lane. LDS dest = wave-uniform base (+lane*16 in HW).
__device__ __forceinline__ void gload16(const unsigned short* g, unsigned char* l){
  __builtin_amdgcn_global_load_lds(
      (const __attribute__((address_space(1))) unsigned int*)g,
      (__attribute__((address_space(3))) unsigned int*)l, 16, 0, 0);
}

// ---- [e][R][C] fp32 -> [e][C][R] bf16 (tiled transpose) ----
template<int R, int C>
__global__ void transpose_cvt_kernel(const float* __restrict__ src, unsigned short* __restrict__ dst){
  __shared__ float tile[32][33];
  const int e  = blockIdx.z;
  const int r0 = blockIdx.y * 32, c0 = blockIdx.x * 32;
  const float* sp = src + (size_t)e * R * C;
  unsigned short* dp = dst + (size_t)e * R * C;
  #pragma unroll
  for (int i = 0; i < 4; i++)
    tile[threadIdx.y + i*8][threadIdx.x] =
        sp[(size_t)(r0 + threadIdx.y + i*8) * C + c0 + threadIdx.x];
  __syncthreads();
  #pragma unroll
  for (int i = 0; i < 4; i++)
    dp[(size_t)(c0 + threadIdx.y + i*8) * R + r0 + threadIdx.x] =
        f2bf(tile[threadIdx.x][threadIdx.y + i*8]);
}

// ---- router: block = 32 tokens, 256 threads (unchanged) ----
__global__ __launch_bounds__(256)
void router_kernel(const float* __restrict__ x, const float* __restrict__ sel,
                   unsigned short* __restrict__ xb,
                   int* __restrict__ cnt, int* __restrict__ tok,
                   float* __restrict__ gate){
  __shared__ float xs[32][65];
  __shared__ float sel_lds[64][16];
  __shared__ float scr[32][17];
  __shared__ int   lcnt[NE];
  __shared__ int   gb[NE];

  const int tid = threadIdx.x;
  const int t0  = blockIdx.x * 32;
  if (tid < NE) lcnt[tid] = 0;

  const int stok = tid >> 3, dseg = tid & 7;
  const int tokc = tid & 31, eg  = tid >> 5;
  float acc0 = 0.f, acc1 = 0.f;

  for (int kc = 0; kc < DM; kc += 64){
    __syncthreads();
    {
      int sdd = tid >> 2, se4 = (tid & 3) * 4;
      *reinterpret_cast<float4*>(&sel_lds[sdd][se4]) =
          *reinterpret_cast<const float4*>(sel + (size_t)(kc + sdd)*NE + se4);
    }
    {
      const float* g = x + (size_t)(t0 + stok)*DM + kc + dseg*8;
      float4 a = reinterpret_cast<const float4*>(g)[0];
      float4 b = reinterpret_cast<const float4*>(g)[1];
      ushort8 r;
      r[0]=f2bf(a.x); r[1]=f2bf(a.y); r[2]=f2bf(a.z); r[3]=f2bf(a.w);
      r[4]=f2bf(b.x); r[5]=f2bf(b.y); r[6]=f2bf(b.z); r[7]=f2bf(b.w);
      *reinterpret_cast<ushort8*>(xb + (size_t)(t0 + stok)*DM + kc + dseg*8) = r;
      float* xr = &xs[stok][dseg*8];
      xr[0]=a.x; xr[1]=a.y; xr[2]=a.z; xr[3]=a.w;
      xr[4]=b.x; xr[5]=b.y; xr[6]=b.z; xr[7]=b.w;
    }
    __syncthreads();
    #pragma unroll 8
    for (int dd = 0; dd < 64; dd++){
      float xv = xs[tokc][dd];
      float2 s = *reinterpret_cast<const float2*>(&sel_lds[dd][eg*2]);
      acc0 += xv * s.x;
      acc1 += xv * s.y;
    }
  }
  scr[tokc][eg*2]   = acc0;
  scr[tokc][eg*2+1] = acc1;
  __syncthreads();

  int best[TOPK]; float gv[TOPK]; int loff[TOPK];
  if (tid < 32){
    unsigned used = 0;
    for (int k = 0; k < TOPK; k++){
      int be = 0; float bv = -1e30f;
      #pragma unroll
      for (int e = 0; e < NE; e++){      // strict > keeps lowest index on tie
        float v = scr[tid][e];
        bool ok = !((used >> e) & 1u) && (v > bv);
        if (ok){ bv = v; be = e; }
      }
      used |= 1u << be;
      best[k] = be;
      gv[k]   = 1.f / (1.f + expf(-bv));
      loff[k] = atomicAdd(&lcnt[be], 1);
    }
  }
  __syncthreads();
  if (tid < NE) gb[tid] = atomicAdd(&cnt[tid], lcnt[tid]);
  __syncthreads();
  if (tid < 32){
    int t = t0 + tid;
    #pragma unroll
    for (int k = 0; k < TOPK; k++){
      int pos = gb[best[k]] + loff[k];
      tok[best[k]*CAP + pos]  = t | (k << 16);   // token + rank tag
      gate[best[k]*CAP + pos] = gv[k];
    }
  }
}

// ---- grouped expert FFN: 64-token block, LEAN LDS (~74KB) -> 2 blocks/CU so
//      cross-block wave overlap fills the per-chunk barrier drains (m114).
//      GEMM1: BK=32 dbuf {X 4KB + K 16KB}. GEMM2: V staged [256d][32s] dbuf.
//      XOR-slot swizzle everywhere; setprio(1) around MFMA clusters. ----
__global__ __launch_bounds__(512, 4)
void ffn_kernel(const unsigned short* __restrict__ xb,   // [NT][DM] bf16
                const unsigned short* __restrict__ kT,   // [e][s=256][d=1024] bf16
                const unsigned short* __restrict__ vT,   // [e][d=1024][s=256] bf16
                const int* __restrict__ cnt, const int* __restrict__ tok,
                const float* __restrict__ gate,
                unsigned short* __restrict__ part){      // [4][NT][DM] fp16
  const int e  = blockIdx.x & (NE-1);
  const int n  = cnt[e];
  const int t0 = (blockIdx.x >> 4) * 64;
  if (t0 >= n) return;                      // block-uniform
  const int rows = min(64, n - t0);

  // sh: GEMM1 dbuf {X[64][32] 4KB @0 + K[256][32] 16KB @4096} x2 (stride 20480);
  //     GEMM2 aliases as vs[256][32] 16KB x2 (@0, @16384). Total 40KB.
  __shared__ __align__(16) unsigned char sh[40960];
  __shared__ __align__(16) unsigned char hsb[64*512];    // H [64][256] bf16, swizzled
  __shared__ int   toks[64];
  __shared__ int   rnk[64];
  __shared__ float gts[64];

  const int tid  = threadIdx.x;
  const int lane = tid & 63;
  const int wv   = tid >> 6;                // 8 waves
  const int lr   = lane & 15;
  const int kb16 = (lane >> 4) << 4;        // k-group byte offset
  const int hi4  = (lane >> 4) * 4;
  const int xo4  = (lr & 3) << 4;           // swizzle for 64B-row tiles
  const int xo8  = (lr & 7) << 4;           // swizzle for 512B-row hsb

  if (tid < 64){
    int idx = t0 + tid;
    int raw = tok[e*CAP + (idx < n ? idx : t0)];
    toks[tid] = raw & 0xFFFF;
    rnk[tid]  = raw >> 16;
    gts[tid]  = (idx < n) ? gate[e*CAP + idx] : 0.f;
  }
  __syncthreads();

  const unsigned short* kTe = kT + (size_t)e * ES * DM;
  const unsigned short* vTe = vT + (size_t)e * DM * ES;

  // staging maps: thread -> (row = tid>>2, slot = tid&3), source col pre-swizzled
  const int srow = tid >> 2;                       // 0..127
  const int scol = ((tid & 3) ^ (srow & 3)) * 8;
  const unsigned short* xsrc  = xb  + (size_t)toks[srow & 63]*DM + scol;  // waves 0-3 only
  const unsigned short* ksrc0 = kTe + (size_t)srow*DM         + scol;
  const unsigned short* ksrc1 = kTe + (size_t)(128 + srow)*DM + scol;
  const unsigned short* vsrc0 = vTe + (size_t)srow*ES         + scol;
  const unsigned short* vsrc1 = vTe + (size_t)(128 + srow)*ES + scol;

  const int mh = wv >> 2;                   // token half (32 rows)
  const int nq = wv & 3;                    // S/d quarter (64 cols)

  // prologue: stage GEMM1 chunk 0
  if (wv < 4) gload16(xsrc, sh + wv*1024);
  gload16(ksrc0, sh + 4096 + wv*1024);
  gload16(ksrc1, sh + 4096 + 8192 + wv*1024);

  const f32x4 fz = {0.f,0.f,0.f,0.f};
  f32x4 acc1[2][4];
  #pragma unroll
  for (int m = 0; m < 2; m++)
    #pragma unroll
    for (int nn = 0; nn < 4; nn++) acc1[m][nn] = fz;

  __syncthreads();                          // chunk 0 staged

  // ---- GEMM1: H[64][256] = X_tile @ K_e, BK=32, 32 chunks ----
  int q = 0;
  for (int c = 0; c < 32; c++){
    if (c < 31){
      int kc = (c+1)*32;
      unsigned char* bb = sh + (q^1)*20480;
      if (wv < 4) gload16(xsrc + kc, bb + wv*1024);
      gload16(ksrc0 + kc, bb + 4096 + wv*1024);
      gload16(ksrc1 + kc, bb + 4096 + 8192 + wv*1024);
    } else {
      // stage V chunk 0 (pass 0, s 0..31) into vs buf0 = sh+0 (GEMM1 buf0 dead)
      gload16(vsrc0, sh + wv*1024);
      gload16(vsrc1, sh + 8192 + wv*1024);
    }
    const unsigned char* xl = sh + q*20480;
    const unsigned char* kl = xl + 4096;
    short8 a[2], b[4];
    #pragma unroll
    for (int m = 0; m < 2; m++)
      a[m] = *reinterpret_cast<const short8*>(xl + (mh*32 + m*16 + lr)*64 + (kb16 ^ xo4));
    #pragma unroll
    for (int nn = 0; nn < 4; nn++)
      b[nn] = *reinterpret_cast<const short8*>(kl + (nq*64 + nn*16 + lr)*64 + (kb16 ^ xo4));
    __builtin_amdgcn_s_setprio(1);
    #pragma unroll
    for (int nn = 0; nn < 4; nn++)
      #pragma unroll
      for (int m = 0; m < 2; m++)
        acc1[m][nn] = __builtin_amdgcn_mfma_f32_16x16x32_bf16(a[m], b[nn], acc1[m][nn], 0,0,0);
    __builtin_amdgcn_s_setprio(0);
    __syncthreads();
    q ^= 1;
  }

  // H = bf16(gate * relu(acc1)) -> swizzled hsb
  #pragma unroll
  for (int m = 0; m < 2; m++)
    #pragma unroll
    for (int j = 0; j < 4; j++){
      int row = mh*32 + m*16 + hi4 + j;     // C/D: col=lane&15, row=(lane>>4)*4+j
      float g = gts[row];
      unsigned char* rbase = hsb + row*512;
      int rxo = (row & 7) << 4;
      #pragma unroll
      for (int nn = 0; nn < 4; nn++){
        int colb = (nq*64 + nn*16 + lr) * 2;
        float h = fmaxf(acc1[m][nn][j], 0.f) * g;
        *reinterpret_cast<unsigned short*>(rbase + (colb ^ rxo)) = f2bf(h);
      }
    }
  __syncthreads();                          // hsb visible; vs chunk 0 already drained

  // ---- GEMM2: part = H @ V_e. 4 d-passes (256 each) x 8 s-chunks (32 each). ----
  f32x4 acc2[2][4];
  #pragma unroll
  for (int m = 0; m < 2; m++)
    #pragma unroll
    for (int nn = 0; nn < 4; nn++) acc2[m][nn] = fz;

  for (int cc = 0; cc < 32; cc++){
    if (cc < 31){
      int nx = cc + 1;
      unsigned char* vb = sh + (nx & 1)*16384;
      const size_t soff = (size_t)(nx >> 3)*256*ES + (nx & 7)*32;
      gload16(vsrc0 + soff, vb + wv*1024);
      gload16(vsrc1 + soff, vb + 8192 + wv*1024);
    }
    const unsigned char* vl = sh + (cc & 1)*16384;
    const int sb = (cc & 7) * 64;
    short8 a[2], b[4];
    #pragma unroll
    for (int m = 0; m < 2; m++)
      a[m] = *reinterpret_cast<const short8*>(hsb + (mh*32 + m*16 + lr)*512 + ((sb + kb16) ^ xo8));
    #pragma unroll
    for (int nn = 0; nn < 4; nn++)
      b[nn] = *reinterpret_cast<const short8*>(vl + (nq*64 + nn*16 + lr)*64 + (kb16 ^ xo4));
    __builtin_amdgcn_s_setprio(1);
    #pragma unroll
    for (int nn = 0; nn < 4; nn++)
      #pragma unroll
      for (int m = 0; m < 2; m++)
        acc2[m][nn] = __builtin_amdgcn_mfma_f32_16x16x32_bf16(a[m], b[nn], acc2[m][nn], 0,0,0);
    __builtin_amdgcn_s_setprio(0);

    if ((cc & 7) == 7){                     // end of a d-pass: write + reset
      int p4 = cc >> 3;
      #pragma unroll
      for (int m = 0; m < 2; m++)
        #pragma unroll
        for (int j = 0; j < 4; j++){
          int tokl = mh*32 + m*16 + hi4 + j;
          if (tokl < rows){
            unsigned short* pb = part + ((size_t)rnk[tokl]*NT + toks[tokl])*DM
                                      + p4*256 + nq*64 + lr;
            #pragma unroll
            for (int nn = 0; nn < 4; nn++)
              pb[nn*16] = f2h(acc2[m][nn][j]);
          }
        }
      #pragma unroll
      for (int m = 0; m < 2; m++)
        #pragma unroll
        for (int nn = 0; nn < 4; nn++) acc2[m][nn] = fz;
    }
    __syncthreads();
  }
}

// ---- gather: out[t][d] = sum_k part[k][t][d]; also writes reg_loss = 0 ----
__global__ __launch_bounds__(256)
void gather_kernel(const unsigned short* __restrict__ part, float* __restrict__ out){
  const size_t i   = (size_t)blockIdx.x * blockDim.x + threadIdx.x;
  const size_t off = i * 8;
  float s[8];
  #pragma unroll
  for (int j = 0; j < 8; j++) s[j] = 0.f;
  #pragma unroll
  for (int k = 0; k < TOPK; k++){
    ushort8 v = *reinterpret_cast<const ushort8*>(part + (size_t)k*NT*DM + off);
    #pragma unroll
    for (int j = 0; j < 8; j++) s[j] += h2f(v[j]);
  }
  float4 lo = {s[0], s[1], s[2], s[3]};
  float4 hi = {s[4], s[5], s[6], s[7]};
  reinterpret_cast<float4*>(out + off)[0] = lo;
  reinterpret_cast<float4*>(out + off)[1] = hi;
  if (i == 0) out[(size_t)NT*DM] = 0.f;   // reg_loss
}

extern "C" void kernel_launch(void* const* d_in, const int* in_sizes, int n_in,
                              void* d_out, int out_size, void* d_ws, size_t ws_size,
                              hipStream_t stream){
  const float* hidden = (const float*)d_in[0];   // [4,2048,1024]
  const float* sel    = (const float*)d_in[1];   // [1024,16]
  const float* keys   = (const float*)d_in[2];   // [16,1024,256]
  const float* values = (const float*)d_in[3];   // [16,256,1024]
  float* out = (float*)d_out;

  char* ws = (char*)d_ws;
  unsigned short* xb = (unsigned short*)ws;                              // 16 MB
  unsigned short* kT = (unsigned short*)(ws + (size_t)16*1024*1024);     //  8 MB
  unsigned short* vT = (unsigned short*)(ws + (size_t)24*1024*1024);     //  8 MB
  int*   cnt  = (int*)  (ws + (size_t)32*1024*1024);                     // 64 B
  int*   tok  = (int*)  (ws + (size_t)32*1024*1024 + 1024);              // 512 KB
  float* gate = (float*)(ws + (size_t)32*1024*1024 + 1024
                            + (size_t)NE*CAP*sizeof(int));               // 512 KB
  unsigned short* part = (unsigned short*)(ws + (size_t)34*1024*1024);   // 64 MB fp16 [4][NT][DM]

  hipMemsetAsync(cnt, 0, NE * sizeof(int), stream);

  transpose_cvt_kernel<DM, ES><<<dim3(ES/32, DM/32, NE), dim3(32,8), 0, stream>>>(keys, kT);
  transpose_cvt_kernel<ES, DM><<<dim3(DM/32, ES/32, NE), dim3(32,8), 0, stream>>>(values, vT);
  router_kernel<<<NT/32, 256, 0, stream>>>(hidden, sel, xb, cnt, tok, gate);
  ffn_kernel<<<(CAP/64)*NE, 512, 0, stream>>>(xb, kT, vT, cnt, tok, gate, part);
  gather_kernel<<<(NT*DM/8)/256, 256, 0, stream>>>(part, out);
}